// Round 2
// baseline (3051.615 us; speedup 1.0000x reference)
//
#include <hip/hip_runtime.h>
#include <math.h>

// ---------------- compile-time sizes ----------------
namespace {
constexpr int B_ = 8, T_ = 128, D_ = 512, C_ = 1000, L_ = 8, U_ = 16, E_ = 256, H_ = 4;
constexpr int DH_ = D_ / H_;      // 128
constexpr int E4_ = 4 * E_;       // 1024
constexpr int D4_ = 4 * D_;       // 2048
constexpr int TU_ = T_ * U_;      // 2048
constexpr int HC_ = H_ * C_;      // 4000
constexpr float SCALE_ = 0.088388347648318447f; // 1/sqrt(128)

// ---------------- ws layout (float offsets) ----------------
constexpr size_t Z_CTX  = 0;                                  // 2*C*4E (dead after LSTM; reused below)
constexpr size_t H_F    = Z_CTX + 2ul * C_ * E4_;
constexpr size_t C_F    = H_F  + (size_t)C_ * E_;
constexpr size_t H_Bo   = C_F  + (size_t)C_ * E_;
constexpr size_t C_Bo   = H_Bo + (size_t)C_ * E_;
constexpr size_t HIST_C = C_Bo + (size_t)C_ * E_;             // B*D
constexpr size_t HF_ALL = HIST_C + (size_t)B_ * D_;
constexpr size_t HB_ALL = HF_ALL + (size_t)C_ * L_ * E_;
constexpr size_t CATM   = HB_ALL + (size_t)C_ * L_ * E_;      // C*2E
constexpr size_t CTXM   = CATM + (size_t)C_ * 2 * E_;         // C*D
constexpr size_t K_WS   = CTXM + (size_t)C_ * D_;
constexpr size_t V_WS   = K_WS + (size_t)C_ * D_;
constexpr size_t HXP    = V_WS + (size_t)C_ * D_;             // B*U*4D
constexpr size_t HALL   = HXP + (size_t)B_ * U_ * D4_;        // B*U*D
constexpr size_t HPROJ  = HALL + (size_t)B_ * U_ * D_;
constexpr size_t MP_    = HPROJ + (size_t)B_ * U_ * D_;       // B*T*D
constexpr size_t QM_    = MP_ + (size_t)B_ * T_ * D_;
constexpr size_t QH_    = QM_ + (size_t)B_ * T_ * D_;         // B*U*D
constexpr size_t SM_    = QH_ + (size_t)B_ * U_ * D_;         // B*T*H*C (becomes EM in-place)
constexpr size_t SH_    = SM_ + (size_t)B_ * T_ * HC_;        // B*U*H*C (becomes EH in-place)
constexpr size_t AOUT_  = SH_ + (size_t)B_ * U_ * HC_;        // B*TU*D
constexpr size_t OFIN_  = AOUT_ + (size_t)B_ * TU_ * D_;      // B*TU*D
constexpr size_t BITS_  = OFIN_ + (size_t)B_ * TU_ * D_;      // 16384 bytes
constexpr size_t USEL_  = BITS_ + 4096;                       // B*T ints
constexpr size_t WS_NEED = USEL_ + (size_t)B_ * T_;
// reuse the (dead) Z_CTX region for softmax side-buffers:
constexpr size_t SMSUM  = Z_CTX;                              // B*T*C  (pre-multiplied by 1/4)
constexpr size_t SHSUM  = Z_CTX + (size_t)B_ * T_ * C_;       // B*U*C  (pre-multiplied by 1/4)
constexpr size_t DEN_   = SHSUM + (size_t)B_ * U_ * C_;       // B*T*U*H
} // namespace

__device__ __forceinline__ float fsig(float x)  { return 1.f / (1.f + __expf(-x)); }
__device__ __forceinline__ float ftanh(float x) { return 1.f - 2.f / (__expf(2.f * x) + 1.f); }

// ---------------- generic NT GEMM (X @ W^T), 64x128 tile, 4x8 micro ----------------
struct GemmP {
  const float* A1; int lda1;
  const int* ridx; int ridx_stride; int ridx_off;  // optional row gather on A1
  const float* A2; int lda2;                       // optional K-concat source
  int K1, K2;
  const float* W1; int ldw1;
  const float* W2; int ldw2;
  const float* bias;                               // optional len-N
  float* out; int ldc;
  int M, N;
  float scale;
  int a_zoff, w_zoff, c_zoff;                      // per-blockIdx.z pointer offsets
};

__device__ __forceinline__ void gemm_core(const GemmP& g, int z) {
  __shared__ float As[16][68];
  __shared__ float Ws[16][132];
  const float* A1 = g.A1 + (long)z * g.a_zoff;
  const float* W1 = g.W1 + (long)z * g.w_zoff;
  float* out = g.out + (long)z * g.c_zoff;
  const int m0 = blockIdx.y * 64;
  const int n0 = blockIdx.x * 128;
  const int tid = threadIdx.x;
  const int lk = tid & 15, lr = tid >> 4;
  const int tx = tid & 15, ty = tid >> 4;
  float acc[4][8] = {};
  const int K = g.K1 + g.K2;
  int arow[4];
#pragma unroll
  for (int p = 0; p < 4; ++p) {
    const int gm = m0 + lr + p * 16;
    if (gm < g.M) arow[p] = g.ridx ? g.ridx[gm * g.ridx_stride + g.ridx_off] : gm;
    else arow[p] = -1;
  }
  for (int k0 = 0; k0 < K; k0 += 16) {
    const int kk = k0 + lk;
    const bool inK1 = kk < g.K1;
#pragma unroll
    for (int p = 0; p < 4; ++p) {
      const int r = lr + p * 16;
      float vA = 0.f;
      if (arow[p] >= 0) {
        vA = inK1 ? A1[(long)arow[p] * g.lda1 + kk]
                  : g.A2[(long)(m0 + r) * g.lda2 + (kk - g.K1)];
      }
      As[lk][r] = vA;
    }
#pragma unroll
    for (int p = 0; p < 8; ++p) {
      const int r = lr + p * 16;
      const int gn = n0 + r;
      float vW = 0.f;
      if (gn < g.N) {
        vW = inK1 ? W1[(long)gn * g.ldw1 + kk]
                  : g.W2[(long)gn * g.ldw2 + (kk - g.K1)];
      }
      Ws[lk][r] = vW;
    }
    __syncthreads();
#pragma unroll
    for (int k = 0; k < 16; ++k) {
      const float4 a  = *(const float4*)&As[k][ty * 4];
      const float4 w0 = *(const float4*)&Ws[k][tx * 8];
      const float4 w1 = *(const float4*)&Ws[k][tx * 8 + 4];
      acc[0][0] += a.x * w0.x; acc[0][1] += a.x * w0.y; acc[0][2] += a.x * w0.z; acc[0][3] += a.x * w0.w;
      acc[0][4] += a.x * w1.x; acc[0][5] += a.x * w1.y; acc[0][6] += a.x * w1.z; acc[0][7] += a.x * w1.w;
      acc[1][0] += a.y * w0.x; acc[1][1] += a.y * w0.y; acc[1][2] += a.y * w0.z; acc[1][3] += a.y * w0.w;
      acc[1][4] += a.y * w1.x; acc[1][5] += a.y * w1.y; acc[1][6] += a.y * w1.z; acc[1][7] += a.y * w1.w;
      acc[2][0] += a.z * w0.x; acc[2][1] += a.z * w0.y; acc[2][2] += a.z * w0.z; acc[2][3] += a.z * w0.w;
      acc[2][4] += a.z * w1.x; acc[2][5] += a.z * w1.y; acc[2][6] += a.z * w1.z; acc[2][7] += a.z * w1.w;
      acc[3][0] += a.w * w0.x; acc[3][1] += a.w * w0.y; acc[3][2] += a.w * w0.z; acc[3][3] += a.w * w0.w;
      acc[3][4] += a.w * w1.x; acc[3][5] += a.w * w1.y; acc[3][6] += a.w * w1.z; acc[3][7] += a.w * w1.w;
    }
    __syncthreads();
  }
#pragma unroll
  for (int i = 0; i < 4; ++i) {
    const int gm = m0 + ty * 4 + i;
    if (gm >= g.M) continue;
#pragma unroll
    for (int j = 0; j < 8; ++j) {
      const int gn = n0 + tx * 8 + j;
      if (gn >= g.N) continue;
      float v = acc[i][j];
      if (g.bias) v += g.bias[gn];
      out[(long)gm * g.ldc + gn] = v * g.scale;
    }
  }
}

__global__ __launch_bounds__(256) void k_gemm(GemmP p) { gemm_core(p, blockIdx.z); }
__global__ __launch_bounds__(256) void k_gemm2(GemmP p0, GemmP p1) {
  if (blockIdx.z) gemm_core(p1, 0); else gemm_core(p0, 0);
}

// ---------------- ctx LSTM gates (both directions) ----------------
__global__ __launch_bounds__(256) void k_ctx_gates(
    const float* __restrict__ z_ws,
    float* __restrict__ h_f, float* __restrict__ c_f,
    float* __restrict__ h_b, float* __restrict__ c_b,
    float* __restrict__ hf_all, float* __restrict__ hb_all, int t) {
  int idx = blockIdx.x * 256 + threadIdx.x;
  if (idx >= C_ * E_) return;
  int dir = blockIdx.y;
  int c = idx / E_, e = idx - c * E_;
  const float* z = z_ws + (size_t)dir * C_ * E4_ + (size_t)c * E4_;
  float zi = z[e], zf = z[e + E_], zg = z[e + 2 * E_], zo = z[e + 3 * E_];
  float* cs = dir ? c_b : c_f;
  float* hs = dir ? h_b : h_f;
  float cn = fsig(zf) * cs[idx] + fsig(zi) * ftanh(zg);
  float hn = fsig(zo) * ftanh(cn);
  cs[idx] = cn; hs[idx] = hn;
  int lpos = dir ? (L_ - 1 - t) : t;
  (dir ? hb_all : hf_all)[((size_t)c * L_ + lpos) * E_ + e] = hn;
}

// ---------------- masked mean over L of concat(hf,hb) ----------------
__global__ __launch_bounds__(256) void k_ctx_mean(
    const float* __restrict__ hf_all, const float* __restrict__ hb_all,
    const int* __restrict__ ilens, float* __restrict__ cat_mean) {
  int idx = blockIdx.x * 256 + threadIdx.x;
  if (idx >= C_ * 2 * E_) return;
  int c = idx / (2 * E_), e = idx - c * 2 * E_;
  const float* src = (e < E_) ? hf_all : hb_all;
  int ee = e & (E_ - 1);
  int il = ilens[c];
  float s = 0.f;
#pragma unroll
  for (int l = 0; l < L_; ++l)
    if (l < il) s += src[((size_t)c * L_ + l) * E_ + ee];
  cat_mean[idx] = s / (float)il;
}

// ---------------- hist LSTM: one step, gates fused ----------------
__global__ __launch_bounds__(64) void k_hist_step(
    const float* __restrict__ xproj, const float* __restrict__ Whh,
    float* __restrict__ hall, float* __restrict__ c_st, int u) {
  __shared__ float hs[B_ * D_];
  int tid = threadIdx.x;
  for (int i = tid; i < B_ * D_; i += 64) {
    int bb = i >> 9, ee = i & 511;
    hs[i] = (u == 0) ? 0.f : hall[((size_t)bb * U_ + (u - 1)) * D_ + ee];
  }
  __syncthreads();
  int g = blockIdx.x * 64 + tid;
  int b = g >> 9, e = g & 511;
  const float* xp = xproj + ((size_t)b * U_ + u) * D4_;
  float zi = xp[e], zf = xp[e + D_], zg = xp[e + 2 * D_], zo = xp[e + 3 * D_];
  const float4* w0 = (const float4*)(Whh + (size_t)e * D_);
  const float4* w1 = (const float4*)(Whh + (size_t)(e + D_) * D_);
  const float4* w2 = (const float4*)(Whh + (size_t)(e + 2 * D_) * D_);
  const float4* w3 = (const float4*)(Whh + (size_t)(e + 3 * D_) * D_);
  const float4* hv = (const float4*)(hs + (size_t)b * D_);
#pragma unroll 4
  for (int k = 0; k < D_ / 4; ++k) {
    float4 h4 = hv[k];
    float4 a = w0[k]; zi += a.x * h4.x + a.y * h4.y + a.z * h4.z + a.w * h4.w;
    float4 bb4 = w1[k]; zf += bb4.x * h4.x + bb4.y * h4.y + bb4.z * h4.z + bb4.w * h4.w;
    float4 cc4 = w2[k]; zg += cc4.x * h4.x + cc4.y * h4.y + cc4.z * h4.z + cc4.w * h4.w;
    float4 dd4 = w3[k]; zo += dd4.x * h4.x + dd4.y * h4.y + dd4.z * h4.z + dd4.w * h4.w;
  }
  float cn = fsig(zf) * c_st[g] + fsig(zi) * ftanh(zg);
  c_st[g] = cn;
  hall[((size_t)b * U_ + u) * D_ + e] = fsig(zo) * ftanh(cn);
}

// ---------------- row-wise exp: Sm->EM in place (+ head-sum for logit) ----------------
// grid.x = B*T + B*U blocks; 256 threads (4 waves = 4 heads)
__global__ __launch_bounds__(256) void k_rowexp(
    float* __restrict__ Sm, float* __restrict__ Sh,
    float* __restrict__ SmS, float* __restrict__ ShS) {
  int row = blockIdx.x;
  float* base; float* sumo;
  if (row < B_ * T_) { base = Sm + (size_t)row * HC_; sumo = SmS + (size_t)row * C_; }
  else { int r2 = row - B_ * T_; base = Sh + (size_t)r2 * HC_; sumo = ShS + (size_t)r2 * C_; }
  int tid = threadIdx.x;
  for (int c = tid; c < C_; c += 256) {
    float s = base[c] + base[C_ + c] + base[2 * C_ + c] + base[3 * C_ + c];
    sumo[c] = 0.25f * s;
  }
  __syncthreads();
  int h = tid >> 6, lane = tid & 63;
  float* p = base + (size_t)h * C_;
  float mx = -1e30f;
  for (int c = lane; c < C_; c += 64) mx = fmaxf(mx, p[c]);
#pragma unroll
  for (int o = 32; o; o >>= 1) mx = fmaxf(mx, __shfl_xor(mx, o));
  for (int c = lane; c < C_; c += 64) p[c] = __expf(p[c] - mx);
}

// ---------------- prob/logit outputs + denominators ----------------
// block per (b,t), 256 threads
__global__ __launch_bounds__(256) void k_problogit(
    const float* __restrict__ EM, const float* __restrict__ EH,
    const float* __restrict__ SmS, const float* __restrict__ ShS,
    float* __restrict__ den, float* __restrict__ prob, float* __restrict__ logit) {
  __shared__ float sEM[H_][1008];
  __shared__ float sSS[1000];
  __shared__ float sInv[H_];
  int bt = blockIdx.x;
  int b = bt >> 7;
  int tid = threadIdx.x;
  for (int i = tid; i < H_ * C_; i += 256) sEM[i / C_][i % C_] = EM[(size_t)bt * HC_ + i];
  for (int c = tid; c < C_; c += 256) sSS[c] = SmS[(size_t)bt * C_ + c];
  __syncthreads();
  int h = tid >> 6, lane = tid & 63;
  for (int u = 0; u < U_; ++u) {
    const float* ehp = EH + (((size_t)b * U_ + u) * H_ + h) * C_;
    float s = 0.f;
    for (int c = lane; c < C_; c += 64) s += sEM[h][c] * ehp[c];
#pragma unroll
    for (int o = 32; o; o >>= 1) s += __shfl_xor(s, o);
    if (lane == 0) {
      sInv[h] = 1.f / s;
      den[((size_t)bt * U_ + u) * H_ + h] = s;
    }
    __syncthreads();
    const float i0 = sInv[0] * 0.25f, i1 = sInv[1] * 0.25f;
    const float i2 = sInv[2] * 0.25f, i3 = sInv[3] * 0.25f;
    const float* eh0 = EH + ((size_t)b * U_ + u) * HC_;
    const float* shs = ShS + ((size_t)b * U_ + u) * C_;
    size_t obase = ((size_t)bt * U_ + u) * C_;
    for (int c = tid; c < C_; c += 256) {
      float pr = sEM[0][c] * eh0[c] * i0 + sEM[1][c] * eh0[C_ + c] * i1
               + sEM[2][c] * eh0[2 * C_ + c] * i2 + sEM[3][c] * eh0[3 * C_ + c] * i3;
      prob[obase + c] = pr;
      logit[obase + c] = sSS[c] + shs[c];
    }
    __syncthreads();
  }
}

// ---------------- PV: out[q,d] = (1/D) * sum_c EM[t,c]*EH[u,c]*V[c,d] ----------------
// grid (16 qtiles of 8t, 2 dblks of 64, B*H); 256 threads; micro 8t x 4d, u = ty
__global__ __launch_bounds__(256) void k_pv(
    const float* __restrict__ EM, const float* __restrict__ EH,
    const float* __restrict__ den, const float* __restrict__ v,
    float* __restrict__ aout) {
  constexpr int KC = 32;
  __shared__ float EMs[KC][8];
  __shared__ float EHs[KC][16];
  __shared__ float Vs[KC][68];
  const int qt = blockIdx.x;
  const int dblk = blockIdx.y;
  const int z = blockIdx.z;
  const int b = z >> 2, h = z & 3;
  const int t0 = qt * 8;
  const int d0 = dblk * 64;
  const int tid = threadIdx.x;
  const int tx = tid & 15, ty = tid >> 4;   // d = d0 + tx*4 .. +3 ; u = ty
  float acc[8][4] = {};
  for (int c0 = 0; c0 < C_; c0 += KC) {
    {
      int tt = tid >> 5, cc = tid & 31;
      int c = c0 + cc;
      EMs[cc][tt] = (c < C_) ? EM[(((size_t)b * T_ + t0 + tt) * H_ + h) * C_ + c] : 0.f;
    }
#pragma unroll
    for (int p = 0; p < 2; ++p) {
      int i = tid + p * 256;
      int uu = i >> 5, cc = i & 31;
      int c = c0 + cc;
      EHs[cc][uu] = (c < C_) ? EH[(((size_t)b * U_ + uu) * H_ + h) * C_ + c] : 0.f;
    }
#pragma unroll
    for (int p = 0; p < 2; ++p) {
      int i4 = (tid + p * 256) * 4;
      int cc = i4 >> 6, dd = i4 & 63;
      int c = c0 + cc;
      float4 val = make_float4(0.f, 0.f, 0.f, 0.f);
      if (c < C_) val = *(const float4*)&v[(size_t)c * D_ + h * 128 + d0 + dd];
      *(float4*)&Vs[cc][dd] = val;
    }
    __syncthreads();
#pragma unroll
    for (int cc = 0; cc < KC; ++cc) {
      const float eh = EHs[cc][ty];
      const float4 e0 = *(const float4*)&EMs[cc][0];
      const float4 e1 = *(const float4*)&EMs[cc][4];
      const float4 vv = *(const float4*)&Vs[cc][tx * 4];
      const float p0 = e0.x * eh, p1 = e0.y * eh, p2 = e0.z * eh, p3 = e0.w * eh;
      const float p4 = e1.x * eh, p5 = e1.y * eh, p6 = e1.z * eh, p7 = e1.w * eh;
      acc[0][0] += p0 * vv.x; acc[0][1] += p0 * vv.y; acc[0][2] += p0 * vv.z; acc[0][3] += p0 * vv.w;
      acc[1][0] += p1 * vv.x; acc[1][1] += p1 * vv.y; acc[1][2] += p1 * vv.z; acc[1][3] += p1 * vv.w;
      acc[2][0] += p2 * vv.x; acc[2][1] += p2 * vv.y; acc[2][2] += p2 * vv.z; acc[2][3] += p2 * vv.w;
      acc[3][0] += p3 * vv.x; acc[3][1] += p3 * vv.y; acc[3][2] += p3 * vv.z; acc[3][3] += p3 * vv.w;
      acc[4][0] += p4 * vv.x; acc[4][1] += p4 * vv.y; acc[4][2] += p4 * vv.z; acc[4][3] += p4 * vv.w;
      acc[5][0] += p5 * vv.x; acc[5][1] += p5 * vv.y; acc[5][2] += p5 * vv.z; acc[5][3] += p5 * vv.w;
      acc[6][0] += p6 * vv.x; acc[6][1] += p6 * vv.y; acc[6][2] += p6 * vv.z; acc[6][3] += p6 * vv.w;
      acc[7][0] += p7 * vv.x; acc[7][1] += p7 * vv.y; acc[7][2] += p7 * vv.z; acc[7][3] += p7 * vv.w;
    }
    __syncthreads();
  }
#pragma unroll
  for (int i = 0; i < 8; ++i) {
    const int t = t0 + i;
    const float inv = 1.f / den[(((size_t)b * T_ + t) * U_ + ty) * H_ + h];
    float4 o;
    o.x = acc[i][0] * inv; o.y = acc[i][1] * inv; o.z = acc[i][2] * inv; o.w = acc[i][3] * inv;
    const size_t q = (size_t)t * U_ + ty;
    *(float4*)&aout[((size_t)b * TU_ + q) * D_ + h * 128 + d0 + tx * 4] = o;
  }
}

// ---------------- decode scan helpers ----------------
__global__ __launch_bounds__(256) void k_bits(
    const float* __restrict__ prob, const int* __restrict__ hidx,
    unsigned char* __restrict__ bits) {
  int i = blockIdx.x * 256 + threadIdx.x;
  if (i >= B_ * T_ * U_) return;
  int u = i & 15, bt = i >> 4, b = bt >> 7;
  int valid = (u + 1 < U_ - 1) ? (u + 1) : (U_ - 1);
  int tok = hidx[b * U_ + valid];
  size_t base = (size_t)i * C_;
  bits[i] = (prob[base + tok] > prob[base]) ? 1 : 0;
}

__global__ __launch_bounds__(64) void k_scan(
    const unsigned char* __restrict__ bits, int* __restrict__ u_sel) {
  __shared__ unsigned char sb[B_ * T_ * U_];
  int tid = threadIdx.x;
  for (int i = tid; i < B_ * T_ * U_; i += 64) sb[i] = bits[i];
  __syncthreads();
  if (tid < B_) {
    int u = 0;
    for (int t = 0; t < T_; ++t) {
      int uc = (u < U_ - 1) ? u : (U_ - 1);
      u_sel[tid * T_ + t] = uc;
      u = uc + (int)sb[(tid * T_ + t) * U_ + uc];
    }
  }
}

__global__ __launch_bounds__(128) void k_gather_o(
    const float* __restrict__ out_final, const int* __restrict__ u_sel,
    float* __restrict__ o) {
  int bt = blockIdx.x;
  int uc = u_sel[bt];
  const float4* src = (const float4*)(out_final + ((size_t)bt * U_ + uc) * D_);
  float4* dst = (float4*)(o + (size_t)bt * D_);
  dst[threadIdx.x] = src[threadIdx.x];
}

// ---------------- host launch ----------------
extern "C" void kernel_launch(void* const* d_in, const int* in_sizes, int n_in,
                              void* d_out, int out_size, void* d_ws, size_t ws_size,
                              hipStream_t stream) {
  const float* model_embed = (const float*)d_in[0];
  const float* emb_table   = (const float*)d_in[1];
  const float* Wih_f = (const float*)d_in[2];
  const float* Whh_f = (const float*)d_in[3];
  const float* b_f   = (const float*)d_in[4];
  const float* Wih_b = (const float*)d_in[5];
  const float* Whh_b = (const float*)d_in[6];
  const float* b_b   = (const float*)d_in[7];
  const float* ctx_out_W  = (const float*)d_in[8];
  const float* hist_Wih   = (const float*)d_in[9];
  const float* hist_Whh   = (const float*)d_in[10];
  const float* hist_b     = (const float*)d_in[11];
  const float* hist_out_W = (const float*)d_in[12];
  const float* Wq = (const float*)d_in[13];
  const float* Wk = (const float*)d_in[14];
  const float* Wv = (const float*)d_in[15];
  const float* Wo = (const float*)d_in[16];
  const float* acoustic_W = (const float*)d_in[17];
  const int* ctx_idxs = (const int*)d_in[18];
  const int* hidx     = (const int*)d_in[19];
  const int* ilens    = (const int*)d_in[20];

  if (ws_size < WS_NEED * sizeof(float)) return;

  float* ws = (float*)d_ws;
  float* o_out     = (float*)d_out;
  float* logit_out = o_out + (size_t)B_ * T_ * D_;
  float* prob_out  = logit_out + (size_t)B_ * T_ * U_ * C_;

  float* zf = ws + Z_CTX;
  float* zb = ws + Z_CTX + (size_t)C_ * E4_;

  hipMemsetAsync(ws + H_F, 0, 4ul * C_ * E_ * sizeof(float), stream);
  hipMemsetAsync(ws + HIST_C, 0, (size_t)B_ * D_ * sizeof(float), stream);

  // ---- ctx bi-LSTM: 8 steps ----
  for (int t = 0; t < L_; ++t) {
    GemmP pf{};
    pf.A1 = emb_table; pf.lda1 = E_;
    pf.ridx = ctx_idxs; pf.ridx_stride = L_; pf.ridx_off = t;
    pf.A2 = ws + H_F; pf.lda2 = E_;
    pf.K1 = E_; pf.K2 = E_;
    pf.W1 = Wih_f; pf.ldw1 = E_; pf.W2 = Whh_f; pf.ldw2 = E_;
    pf.bias = b_f; pf.out = zf; pf.ldc = E4_; pf.M = C_; pf.N = E4_; pf.scale = 1.f;
    GemmP pb = pf;
    pb.ridx_off = L_ - 1 - t; pb.A2 = ws + H_Bo;
    pb.W1 = Wih_b; pb.W2 = Whh_b; pb.bias = b_b; pb.out = zb;
    k_gemm2<<<dim3(8, 16, 2), 256, 0, stream>>>(pf, pb);
    k_ctx_gates<<<dim3((C_ * E_ + 255) / 256, 2), 256, 0, stream>>>(
        ws + Z_CTX, ws + H_F, ws + C_F, ws + H_Bo, ws + C_Bo,
        ws + HF_ALL, ws + HB_ALL, t);
  }

  // ---- masked mean + ctx_out projection ----
  k_ctx_mean<<<dim3((C_ * 2 * E_ + 255) / 256), 256, 0, stream>>>(
      ws + HF_ALL, ws + HB_ALL, ilens, ws + CATM);
  {
    GemmP p{};
    p.A1 = ws + CATM; p.lda1 = 2 * E_; p.K1 = 2 * E_;
    p.W1 = ctx_out_W; p.ldw1 = 2 * E_;
    p.out = ws + CTXM; p.ldc = D_; p.M = C_; p.N = D_; p.scale = 1.f;
    k_gemm<<<dim3(4, 16, 1), 256, 0, stream>>>(p);
  }

  // ---- k (scaled) and v ----
  {
    GemmP pk{};
    pk.A1 = ws + CTXM; pk.lda1 = D_; pk.K1 = D_;
    pk.W1 = Wk; pk.ldw1 = D_;
    pk.out = ws + K_WS; pk.ldc = D_; pk.M = C_; pk.N = D_; pk.scale = SCALE_;
    GemmP pv = pk;
    pv.W1 = Wv; pv.out = ws + V_WS; pv.scale = 1.f;
    k_gemm2<<<dim3(4, 16, 2), 256, 0, stream>>>(pk, pv);
  }

  // ---- hist LSTM input projection ----
  {
    GemmP p{};
    p.A1 = ws + CTXM; p.lda1 = D_;
    p.ridx = hidx; p.ridx_stride = 1; p.ridx_off = 0;
    p.K1 = D_;
    p.W1 = hist_Wih; p.ldw1 = D_;
    p.bias = hist_b;
    p.out = ws + HXP; p.ldc = D4_; p.M = B_ * U_; p.N = D4_; p.scale = 1.f;
    k_gemm<<<dim3(16, 2, 1), 256, 0, stream>>>(p);
  }

  // ---- hist LSTM recurrence ----
  for (int u = 0; u < U_; ++u) {
    k_hist_step<<<dim3(64), 64, 0, stream>>>(ws + HXP, hist_Whh, ws + HALL, ws + HIST_C, u);
  }

  // ---- hist_out, mp, qm, qh ----
  {
    GemmP p{};
    p.A1 = ws + HALL; p.lda1 = D_; p.K1 = D_;
    p.W1 = hist_out_W; p.ldw1 = D_;
    p.out = ws + HPROJ; p.ldc = D_; p.M = B_ * U_; p.N = D_; p.scale = 1.f;
    k_gemm<<<dim3(4, 2, 1), 256, 0, stream>>>(p);
  }
  {
    GemmP p{};
    p.A1 = model_embed; p.lda1 = D_; p.K1 = D_;
    p.W1 = acoustic_W; p.ldw1 = D_;
    p.out = ws + MP_; p.ldc = D_; p.M = B_ * T_; p.N = D_; p.scale = 1.f;
    k_gemm<<<dim3(4, 16, 1), 256, 0, stream>>>(p);
  }
  {
    GemmP p{};
    p.A1 = ws + MP_; p.lda1 = D_; p.K1 = D_;
    p.W1 = Wq; p.ldw1 = D_;
    p.out = ws + QM_; p.ldc = D_; p.M = B_ * T_; p.N = D_; p.scale = 1.f;
    k_gemm<<<dim3(4, 16, 1), 256, 0, stream>>>(p);
  }
  {
    GemmP p{};
    p.A1 = ws + HPROJ; p.lda1 = D_; p.K1 = D_;
    p.W1 = Wq; p.ldw1 = D_;
    p.out = ws + QH_; p.ldc = D_; p.M = B_ * U_; p.N = D_; p.scale = 1.f;
    k_gemm<<<dim3(4, 2, 1), 256, 0, stream>>>(p);
  }

  // ---- Sm, Sh ----
  {
    GemmP p{};
    p.A1 = ws + QM_; p.lda1 = D_; p.K1 = DH_;
    p.W1 = ws + K_WS; p.ldw1 = D_;
    p.out = ws + SM_; p.ldc = HC_; p.M = B_ * T_; p.N = C_; p.scale = 1.f;
    p.a_zoff = DH_; p.w_zoff = DH_; p.c_zoff = C_;
    k_gemm<<<dim3(8, 16, H_), 256, 0, stream>>>(p);
  }
  {
    GemmP p{};
    p.A1 = ws + QH_; p.lda1 = D_; p.K1 = DH_;
    p.W1 = ws + K_WS; p.ldw1 = D_;
    p.out = ws + SH_; p.ldc = HC_; p.M = B_ * U_; p.N = C_; p.scale = 1.f;
    p.a_zoff = DH_; p.w_zoff = DH_; p.c_zoff = C_;
    k_gemm<<<dim3(8, 2, H_), 256, 0, stream>>>(p);
  }

  // ---- exp factorization + outputs ----
  k_rowexp<<<dim3(B_ * T_ + B_ * U_), 256, 0, stream>>>(
      ws + SM_, ws + SH_, ws + SMSUM, ws + SHSUM);
  k_problogit<<<dim3(B_ * T_), 256, 0, stream>>>(
      ws + SM_, ws + SH_, ws + SMSUM, ws + SHSUM, ws + DEN_, prob_out, logit_out);

  // ---- PV ----
  k_pv<<<dim3(16, 2, B_ * H_), 256, 0, stream>>>(
      ws + SM_, ws + SH_, ws + DEN_, ws + V_WS, ws + AOUT_);

  // ---- Wo projection ----
  {
    GemmP p{};
    p.A1 = ws + AOUT_; p.lda1 = D_; p.K1 = D_;
    p.W1 = Wo; p.ldw1 = D_;
    p.out = ws + OFIN_; p.ldc = D_; p.M = B_ * TU_; p.N = D_; p.scale = 1.f;
    k_gemm<<<dim3(4, 256, 1), 256, 0, stream>>>(p);
  }

  // ---- decode ----
  k_bits<<<dim3(64), 256, 0, stream>>>(prob_out, hidx, (unsigned char*)(ws + BITS_));
  k_scan<<<dim3(1), 64, 0, stream>>>((const unsigned char*)(ws + BITS_), (int*)(ws + USEL_));
  k_gather_o<<<dim3(B_ * T_), 128, 0, stream>>>(ws + OFIN_, (const int*)(ws + USEL_), o_out);
}

// Round 3
// 1952.449 us; speedup vs baseline: 1.5630x; 1.5630x over previous
//
#include <hip/hip_runtime.h>
#include <math.h>

// ---------------- compile-time sizes ----------------
namespace {
constexpr int B_ = 8, T_ = 128, D_ = 512, C_ = 1000, L_ = 8, U_ = 16, E_ = 256, H_ = 4;
constexpr int DH_ = D_ / H_;      // 128
constexpr int E4_ = 4 * E_;       // 1024
constexpr int D4_ = 4 * D_;       // 2048
constexpr int TU_ = T_ * U_;      // 2048
constexpr int HC_ = H_ * C_;      // 4000
constexpr int CL_ = C_ * L_;      // 8000
constexpr float SCALE_ = 0.088388347648318447f; // 1/sqrt(128)

// ---------------- ws layout (float offsets) ----------------
// REGION_A: XZ (16.38M floats, dead after ctx steps) aliases SM/SH/AOUT/OFIN (21.39M)
constexpr size_t SM_    = 0;                                   // B*T*H*C = 4,096,000
constexpr size_t SH_    = SM_ + (size_t)B_ * T_ * HC_;         // B*U*H*C = 512,000
constexpr size_t AOUT_  = SH_ + (size_t)B_ * U_ * HC_;         // B*TU*D = 8,388,608
constexpr size_t OFIN_  = AOUT_ + (size_t)B_ * TU_ * D_;
constexpr size_t REG_A_END = OFIN_ + (size_t)B_ * TU_ * D_;
constexpr size_t XZ_    = 0;                                   // 2*8*1000*1024 = 16,384,000 (alias)
constexpr size_t HPING  = REG_A_END;                           // 2*C*E
constexpr size_t CST    = HPING + 2ul * C_ * E_;               // 2*C*E (adjacent for one memset)
constexpr size_t HPONG  = CST + 2ul * C_ * E_;
constexpr size_t HFALL  = HPONG + 2ul * C_ * E_;               // C*L*E
constexpr size_t HBALL  = HFALL + (size_t)C_ * L_ * E_;
constexpr size_t CATM   = HBALL + (size_t)C_ * L_ * E_;        // C*2E
constexpr size_t CTXM   = CATM + (size_t)C_ * 2 * E_;          // C*D
constexpr size_t KWS    = CTXM + (size_t)C_ * D_;
constexpr size_t VWS    = KWS + (size_t)C_ * D_;
constexpr size_t WQA    = VWS + (size_t)C_ * D_;               // D*D
constexpr size_t WQH    = WQA + (size_t)D_ * D_;               // D*D
constexpr size_t HXP    = WQH + (size_t)D_ * D_;               // B*U*4D
constexpr size_t HALL   = HXP + (size_t)B_ * U_ * D4_;         // B*U*D
constexpr size_t HISTC  = HALL + (size_t)B_ * U_ * D_;         // B*D
constexpr size_t QM_    = HISTC + (size_t)B_ * D_;             // B*T*D
constexpr size_t QH_    = QM_ + (size_t)B_ * T_ * D_;          // B*U*D
constexpr size_t SMSUM  = QH_ + (size_t)B_ * U_ * D_;          // B*T*C
constexpr size_t SHSUM  = SMSUM + (size_t)B_ * T_ * C_;        // B*U*C
constexpr size_t DEN_   = SHSUM + (size_t)B_ * U_ * C_;        // B*T*U*H
constexpr size_t BITS_  = DEN_ + (size_t)B_ * T_ * U_ * H_;    // 16384 B
constexpr size_t USEL_  = BITS_ + 4096;
constexpr size_t WS_NEED = USEL_ + (size_t)B_ * T_;
} // namespace

__device__ __forceinline__ float fsig(float x)  { return 1.f / (1.f + __expf(-x)); }
__device__ __forceinline__ float ftanh(float x) { return 1.f - 2.f / (__expf(2.f * x) + 1.f); }

// ---------------- generic NT GEMM (X @ W^T) ----------------
struct GemmP {
  const float* A1; int lda1;
  const int* ridx; int ridx_stride; int ridx_off;
  int gmode;                     // 1 = ctx-token-gather rows (dir,t,c)
  const float* W1; const float* W1b; int ldw1;
  const float* bias; const float* biasb;
  float* out; int ldc;
  int M, N, K;
  float scale;
  int a_zoff, w_zoff, c_zoff;
};

template <int TN>
__device__ __forceinline__ void gemm_core(const GemmP& g, int z) {
  constexpr int UN = TN / 16;
  __shared__ float As[16][68];
  __shared__ float Ws[16][TN + 4];
  const int m0 = blockIdx.y * 64;
  const int n0 = blockIdx.x * TN;
  if (m0 >= g.M || n0 >= g.N) return;
  const bool hiW = (g.gmode == 1) && (m0 >= CL_);
  const float* A1 = g.A1 + (long)z * g.a_zoff;
  const float* W1 = (hiW ? g.W1b : g.W1) + (long)z * g.w_zoff;
  const float* bias = hiW ? g.biasb : g.bias;
  float* out = g.out + (long)z * g.c_zoff;
  const int tid = threadIdx.x;
  const int lk = tid & 15, lr = tid >> 4;
  const int tx = tid & 15, ty = tid >> 4;
  float acc[4][UN] = {};
  int arow[4];
#pragma unroll
  for (int p = 0; p < 4; ++p) {
    const int gm = m0 + lr + p * 16;
    if (gm >= g.M) { arow[p] = -1; continue; }
    if (g.gmode == 1) {
      int dir = gm / CL_, rr = gm % CL_, t = rr / C_, c = rr % C_;
      arow[p] = g.ridx[c * L_ + (dir ? (L_ - 1 - t) : t)];
    } else {
      arow[p] = g.ridx ? g.ridx[gm * g.ridx_stride + g.ridx_off] : gm;
    }
  }
  for (int k0 = 0; k0 < g.K; k0 += 16) {
    const int kk = k0 + lk;
#pragma unroll
    for (int p = 0; p < 4; ++p) {
      const int r = lr + p * 16;
      As[lk][r] = (arow[p] >= 0) ? A1[(long)arow[p] * g.lda1 + kk] : 0.f;
    }
#pragma unroll
    for (int p = 0; p < UN; ++p) {
      const int r = lr + p * 16;
      const int gn = n0 + r;
      Ws[lk][r] = (gn < g.N) ? W1[(long)gn * g.ldw1 + kk] : 0.f;
    }
    __syncthreads();
#pragma unroll
    for (int k = 0; k < 16; ++k) {
      const float4 a = *(const float4*)&As[k][ty * 4];
#pragma unroll
      for (int q = 0; q < UN / 4; ++q) {
        const float4 w = *(const float4*)&Ws[k][q * 64 + tx * 4];
        acc[0][q*4+0] += a.x * w.x; acc[0][q*4+1] += a.x * w.y; acc[0][q*4+2] += a.x * w.z; acc[0][q*4+3] += a.x * w.w;
        acc[1][q*4+0] += a.y * w.x; acc[1][q*4+1] += a.y * w.y; acc[1][q*4+2] += a.y * w.z; acc[1][q*4+3] += a.y * w.w;
        acc[2][q*4+0] += a.z * w.x; acc[2][q*4+1] += a.z * w.y; acc[2][q*4+2] += a.z * w.z; acc[2][q*4+3] += a.z * w.w;
        acc[3][q*4+0] += a.w * w.x; acc[3][q*4+1] += a.w * w.y; acc[3][q*4+2] += a.w * w.z; acc[3][q*4+3] += a.w * w.w;
      }
    }
    __syncthreads();
  }
#pragma unroll
  for (int i = 0; i < 4; ++i) {
    const int gm = m0 + ty * 4 + i;
    if (gm >= g.M) continue;
#pragma unroll
    for (int q = 0; q < UN / 4; ++q) {
#pragma unroll
      for (int j = 0; j < 4; ++j) {
        const int gn = n0 + q * 64 + tx * 4 + j;
        if (gn >= g.N) continue;
        float v2 = acc[i][q*4+j];
        if (bias) v2 += bias[gn];
        out[(long)gm * g.ldc + gn] = v2 * g.scale;
      }
    }
  }
}

__global__ __launch_bounds__(256) void k_gemm64(GemmP p)  { gemm_core<64>(p, blockIdx.z); }
__global__ __launch_bounds__(256) void k_gemm128(GemmP p) { gemm_core<128>(p, blockIdx.z); }
__global__ __launch_bounds__(256) void k_gemm64x2(GemmP p0, GemmP p1, int zs) {
  int z = blockIdx.z;
  if (z < zs) gemm_core<64>(p0, z); else gemm_core<64>(p1, z - zs);
}

// ---------------- NN GEMM: O = A @ B, all 512x512 (weight folding) ----------------
__global__ __launch_bounds__(256) void k_gemm_nn(
    const float* __restrict__ A0, const float* __restrict__ B0, float* __restrict__ O0,
    const float* __restrict__ A1, const float* __restrict__ B1, float* __restrict__ O1) {
  const float* A = blockIdx.z ? A1 : A0;
  const float* B = blockIdx.z ? B1 : B0;
  float* O = blockIdx.z ? O1 : O0;
  __shared__ float As[16][68];
  __shared__ float Bs[16][68];
  const int m0 = blockIdx.y * 64, n0 = blockIdx.x * 64;
  const int tid = threadIdx.x;
  const int lk = tid & 15, lr = tid >> 4;
  const int tx = tid & 15, ty = tid >> 4;
  float acc[4][4] = {};
  for (int k0 = 0; k0 < 512; k0 += 16) {
#pragma unroll
    for (int p = 0; p < 4; ++p) {
      const int r = lr + p * 16;
      As[lk][r] = A[(long)(m0 + r) * 512 + k0 + lk];
    }
#pragma unroll
    for (int p = 0; p < 4; ++p) {
      int idx = tid + p * 256;
      int kk = idx >> 6, jj = idx & 63;
      Bs[kk][jj] = B[(long)(k0 + kk) * 512 + n0 + jj];
    }
    __syncthreads();
#pragma unroll
    for (int k = 0; k < 16; ++k) {
      const float4 a = *(const float4*)&As[k][ty * 4];
      const float4 w = *(const float4*)&Bs[k][tx * 4];
      acc[0][0] += a.x * w.x; acc[0][1] += a.x * w.y; acc[0][2] += a.x * w.z; acc[0][3] += a.x * w.w;
      acc[1][0] += a.y * w.x; acc[1][1] += a.y * w.y; acc[1][2] += a.y * w.z; acc[1][3] += a.y * w.w;
      acc[2][0] += a.z * w.x; acc[2][1] += a.z * w.y; acc[2][2] += a.z * w.z; acc[2][3] += a.z * w.w;
      acc[3][0] += a.w * w.x; acc[3][1] += a.w * w.y; acc[3][2] += a.w * w.z; acc[3][3] += a.w * w.w;
    }
    __syncthreads();
  }
#pragma unroll
  for (int i = 0; i < 4; ++i)
#pragma unroll
    for (int j = 0; j < 4; ++j)
      O[(long)(m0 + ty * 4 + i) * 512 + n0 + tx * 4 + j] = acc[i][j];
}

// ---------------- ctx LSTM recurrent step: z = xz + h@Whh^T, gates fused ----------------
// grid (4 etiles, 32 ctiles, 2 dirs); 256 thr; block = 32c x 64e x 4 gates, K=256
__global__ __launch_bounds__(256) void k_ctx_step(
    const float* __restrict__ xz,
    const float* __restrict__ Whh_f, const float* __restrict__ Whh_b,
    const float* __restrict__ h_prev, float* __restrict__ h_next,
    float* __restrict__ c_st,
    float* __restrict__ hf_all, float* __restrict__ hb_all, int t) {
  __shared__ float Hs[16][36];
  __shared__ float Wg[4][16][68];
  const int e0 = blockIdx.x * 64;
  const int c0 = blockIdx.y * 32;
  const int dir = blockIdx.z;
  const int tid = threadIdx.x;
  const float* Whh = dir ? Whh_b : Whh_f;
  const float* hp = h_prev + (size_t)dir * C_ * E_;
  const int cy = tid >> 4, ex = tid & 15;
  float acc[4][2][4] = {};
  for (int k0 = 0; k0 < E_; k0 += 16) {
    {
      int idx = tid;
#pragma unroll
      for (int p = 0; p < 2; ++p, idx += 256) {
        int kk = idx & 15, cr = idx >> 4;
        int c = c0 + cr;
        Hs[kk][cr] = (c < C_) ? hp[(size_t)c * E_ + k0 + kk] : 0.f;
      }
    }
    {
      int idx = tid;
#pragma unroll
      for (int p = 0; p < 16; ++p, idx += 256) {
        int kk = idx & 15, rest = idx >> 4;
        int ee = rest & 63, gg = rest >> 6;
        Wg[gg][kk][ee] = Whh[(size_t)(gg * E_ + e0 + ee) * E_ + k0 + kk];
      }
    }
    __syncthreads();
#pragma unroll
    for (int kk = 0; kk < 16; ++kk) {
      const float a0 = Hs[kk][cy * 2];
      const float a1 = Hs[kk][cy * 2 + 1];
#pragma unroll
      for (int gg = 0; gg < 4; ++gg) {
        const float4 w = *(const float4*)&Wg[gg][kk][ex * 4];
        acc[gg][0][0] += a0 * w.x; acc[gg][0][1] += a0 * w.y; acc[gg][0][2] += a0 * w.z; acc[gg][0][3] += a0 * w.w;
        acc[gg][1][0] += a1 * w.x; acc[gg][1][1] += a1 * w.y; acc[gg][1][2] += a1 * w.z; acc[gg][1][3] += a1 * w.w;
      }
    }
    __syncthreads();
  }
  const int lpos = dir ? (L_ - 1 - t) : t;
  float* c_state = c_st + (size_t)dir * C_ * E_;
  float* hn_out = h_next + (size_t)dir * C_ * E_;
  float* hall = dir ? hb_all : hf_all;
  const float* xz_base = xz + ((size_t)dir * L_ + t) * C_ * E4_;
#pragma unroll
  for (int i = 0; i < 2; ++i) {
    const int c = c0 + cy * 2 + i;
    if (c >= C_) continue;
    const int e = e0 + ex * 4;
    const float* xr = xz_base + (size_t)c * E4_;
    float zi[4], zf[4], zg[4], zo[4], cp[4], cn[4], hn[4];
    *(float4*)zi = *(const float4*)&xr[e];
    *(float4*)zf = *(const float4*)&xr[E_ + e];
    *(float4*)zg = *(const float4*)&xr[2 * E_ + e];
    *(float4*)zo = *(const float4*)&xr[3 * E_ + e];
    *(float4*)cp = *(const float4*)&c_state[(size_t)c * E_ + e];
#pragma unroll
    for (int j = 0; j < 4; ++j) {
      float vi = zi[j] + acc[0][i][j];
      float vf = zf[j] + acc[1][i][j];
      float vg = zg[j] + acc[2][i][j];
      float vo = zo[j] + acc[3][i][j];
      cn[j] = fsig(vf) * cp[j] + fsig(vi) * ftanh(vg);
      hn[j] = fsig(vo) * ftanh(cn[j]);
    }
    *(float4*)&c_state[(size_t)c * E_ + e] = *(float4*)cn;
    *(float4*)&hn_out[(size_t)c * E_ + e] = *(float4*)hn;
    *(float4*)&hall[((size_t)c * L_ + lpos) * E_ + e] = *(float4*)hn;
  }
}

// ---------------- masked mean over L of concat(hf,hb) ----------------
__global__ __launch_bounds__(256) void k_ctx_mean(
    const float* __restrict__ hf_all, const float* __restrict__ hb_all,
    const int* __restrict__ ilens, float* __restrict__ cat_mean) {
  int idx = blockIdx.x * 256 + threadIdx.x;
  if (idx >= C_ * 2 * E_) return;
  int c = idx / (2 * E_), e = idx - c * 2 * E_;
  const float* src = (e < E_) ? hf_all : hb_all;
  int ee = e & (E_ - 1);
  int il = ilens[c];
  float s = 0.f;
#pragma unroll
  for (int l = 0; l < L_; ++l)
    if (l < il) s += src[((size_t)c * L_ + l) * E_ + ee];
  cat_mean[idx] = s / (float)il;
}

// ---------------- hist LSTM: one step ----------------
__global__ __launch_bounds__(64) void k_hist_step(
    const float* __restrict__ xproj, const float* __restrict__ Whh,
    float* __restrict__ hall, float* __restrict__ c_st, int u) {
  __shared__ float hs[B_ * D_];
  int tid = threadIdx.x;
  for (int i = tid; i < B_ * D_; i += 64) {
    int bb = i >> 9, ee = i & 511;
    hs[i] = (u == 0) ? 0.f : hall[((size_t)bb * U_ + (u - 1)) * D_ + ee];
  }
  __syncthreads();
  int g = blockIdx.x * 64 + tid;
  int b = g >> 9, e = g & 511;
  const float* xp = xproj + ((size_t)b * U_ + u) * D4_;
  float zi = xp[e], zf = xp[e + D_], zg = xp[e + 2 * D_], zo = xp[e + 3 * D_];
  const float4* w0 = (const float4*)(Whh + (size_t)e * D_);
  const float4* w1 = (const float4*)(Whh + (size_t)(e + D_) * D_);
  const float4* w2 = (const float4*)(Whh + (size_t)(e + 2 * D_) * D_);
  const float4* w3 = (const float4*)(Whh + (size_t)(e + 3 * D_) * D_);
  const float4* hv = (const float4*)(hs + (size_t)b * D_);
#pragma unroll 4
  for (int k = 0; k < D_ / 4; ++k) {
    float4 h4 = hv[k];
    float4 a = w0[k]; zi += a.x * h4.x + a.y * h4.y + a.z * h4.z + a.w * h4.w;
    float4 bb4 = w1[k]; zf += bb4.x * h4.x + bb4.y * h4.y + bb4.z * h4.z + bb4.w * h4.w;
    float4 cc4 = w2[k]; zg += cc4.x * h4.x + cc4.y * h4.y + cc4.z * h4.z + cc4.w * h4.w;
    float4 dd4 = w3[k]; zo += dd4.x * h4.x + dd4.y * h4.y + dd4.z * h4.z + dd4.w * h4.w;
  }
  float cn = fsig(zf) * c_st[g] + fsig(zi) * ftanh(zg);
  c_st[g] = cn;
  hall[((size_t)b * U_ + u) * D_ + e] = fsig(zo) * ftanh(cn);
}

// ---------------- row-wise exp: Sm->EM / Sh->EH in place (+ head-sums) ----------------
__global__ __launch_bounds__(256) void k_rowexp(
    float* __restrict__ Sm, float* __restrict__ Sh,
    float* __restrict__ SmS, float* __restrict__ ShS) {
  int row = blockIdx.x;
  float* base; float* sumo;
  if (row < B_ * T_) { base = Sm + (size_t)row * HC_; sumo = SmS + (size_t)row * C_; }
  else { int r2 = row - B_ * T_; base = Sh + (size_t)r2 * HC_; sumo = ShS + (size_t)r2 * C_; }
  int tid = threadIdx.x;
  for (int c = tid; c < C_; c += 256) {
    float s = base[c] + base[C_ + c] + base[2 * C_ + c] + base[3 * C_ + c];
    sumo[c] = 0.25f * s;
  }
  __syncthreads();
  int h = tid >> 6, lane = tid & 63;
  float* p = base + (size_t)h * C_;
  float mx = -1e30f;
  for (int c = lane; c < C_; c += 64) mx = fmaxf(mx, p[c]);
#pragma unroll
  for (int o = 32; o; o >>= 1) mx = fmaxf(mx, __shfl_xor(mx, o));
  for (int c = lane; c < C_; c += 64) p[c] = __expf(p[c] - mx);
}

// ---------------- prob/logit outputs + denominators ----------------
__global__ __launch_bounds__(256) void k_problogit(
    const float* __restrict__ EM, const float* __restrict__ EH,
    const float* __restrict__ SmS, const float* __restrict__ ShS,
    float* __restrict__ den, float* __restrict__ prob, float* __restrict__ logit) {
  __shared__ float sEM[H_][1008];
  __shared__ float sSS[1000];
  __shared__ float sInv[H_];
  int bt = blockIdx.x;
  int b = bt >> 7;
  int tid = threadIdx.x;
  for (int i = tid; i < H_ * C_; i += 256) sEM[i / C_][i % C_] = EM[(size_t)bt * HC_ + i];
  for (int c = tid; c < C_; c += 256) sSS[c] = SmS[(size_t)bt * C_ + c];
  __syncthreads();
  int h = tid >> 6, lane = tid & 63;
  for (int u = 0; u < U_; ++u) {
    const float* ehp = EH + (((size_t)b * U_ + u) * H_ + h) * C_;
    float s = 0.f;
    for (int c = lane; c < C_; c += 64) s += sEM[h][c] * ehp[c];
#pragma unroll
    for (int o = 32; o; o >>= 1) s += __shfl_xor(s, o);
    if (lane == 0) {
      sInv[h] = 1.f / s;
      den[((size_t)bt * U_ + u) * H_ + h] = s;
    }
    __syncthreads();
    const float i0 = sInv[0] * 0.25f, i1 = sInv[1] * 0.25f;
    const float i2 = sInv[2] * 0.25f, i3 = sInv[3] * 0.25f;
    const float* eh0 = EH + ((size_t)b * U_ + u) * HC_;
    const float* shs = ShS + ((size_t)b * U_ + u) * C_;
    size_t obase = ((size_t)bt * U_ + u) * C_;
    for (int c = tid; c < C_; c += 256) {
      float pr = sEM[0][c] * eh0[c] * i0 + sEM[1][c] * eh0[C_ + c] * i1
               + sEM[2][c] * eh0[2 * C_ + c] * i2 + sEM[3][c] * eh0[3 * C_ + c] * i3;
      prob[obase + c] = pr;
      logit[obase + c] = sSS[c] + shs[c];
    }
    __syncthreads();
  }
}

// ---------------- PV: out[(t,u),d] = (1/den) * sum_c EM[t,c]*EH[u,c]*V[c,d] ----------------
// grid (16 ttiles of 8, B*H); 256 thr; block = 8t x 16u x 128d; micro 8t x (4+4)d, u=ty
__global__ __launch_bounds__(256) void k_pv(
    const float* __restrict__ EM, const float* __restrict__ EH,
    const float* __restrict__ den, const float* __restrict__ vmat,
    float* __restrict__ aout) {
  constexpr int KC = 32;
  __shared__ float EMs[KC][8];
  __shared__ float EHs[KC][16];
  __shared__ float Vs[KC][132];
  const int t0 = blockIdx.x * 8;
  const int z = blockIdx.y;
  const int b = z >> 2, h = z & 3;
  const int tid = threadIdx.x;
  const int tx = tid & 15, ty = tid >> 4;
  float acc[8][2][4] = {};
  for (int c0 = 0; c0 < C_; c0 += KC) {
    {
      int cc = tid & 31, tt = tid >> 5;
      int c = c0 + cc;
      EMs[cc][tt] = (c < C_) ? EM[(((size_t)b * T_ + t0 + tt) * H_ + h) * C_ + c] : 0.f;
    }
#pragma unroll
    for (int p = 0; p < 2; ++p) {
      int i = tid + p * 256;
      int cc = i & 31, uu = i >> 5;
      int c = c0 + cc;
      EHs[cc][uu] = (c < C_) ? EH[(((size_t)b * U_ + uu) * H_ + h) * C_ + c] : 0.f;
    }
#pragma unroll
    for (int p = 0; p < 4; ++p) {
      int ci = tid + p * 256;
      int cc = ci >> 5, j4 = ci & 31;
      int c = c0 + cc;
      float4 val = make_float4(0.f, 0.f, 0.f, 0.f);
      if (c < C_) val = *(const float4*)&vmat[(size_t)c * D_ + h * DH_ + j4 * 4];
      *(float4*)&Vs[cc][j4 * 4] = val;
    }
    __syncthreads();
#pragma unroll
    for (int cc = 0; cc < KC; ++cc) {
      const float eh = EHs[cc][ty];
      const float4 e0 = *(const float4*)&EMs[cc][0];
      const float4 e1 = *(const float4*)&EMs[cc][4];
      const float4 v0 = *(const float4*)&Vs[cc][tx * 4];
      const float4 v1 = *(const float4*)&Vs[cc][64 + tx * 4];
      const float p0 = e0.x * eh, p1 = e0.y * eh, p2 = e0.z * eh, p3 = e0.w * eh;
      const float p4 = e1.x * eh, p5 = e1.y * eh, p6 = e1.z * eh, p7 = e1.w * eh;
      acc[0][0][0] += p0 * v0.x; acc[0][0][1] += p0 * v0.y; acc[0][0][2] += p0 * v0.z; acc[0][0][3] += p0 * v0.w;
      acc[0][1][0] += p0 * v1.x; acc[0][1][1] += p0 * v1.y; acc[0][1][2] += p0 * v1.z; acc[0][1][3] += p0 * v1.w;
      acc[1][0][0] += p1 * v0.x; acc[1][0][1] += p1 * v0.y; acc[1][0][2] += p1 * v0.z; acc[1][0][3] += p1 * v0.w;
      acc[1][1][0] += p1 * v1.x; acc[1][1][1] += p1 * v1.y; acc[1][1][2] += p1 * v1.z; acc[1][1][3] += p1 * v1.w;
      acc[2][0][0] += p2 * v0.x; acc[2][0][1] += p2 * v0.y; acc[2][0][2] += p2 * v0.z; acc[2][0][3] += p2 * v0.w;
      acc[2][1][0] += p2 * v1.x; acc[2][1][1] += p2 * v1.y; acc[2][1][2] += p2 * v1.z; acc[2][1][3] += p2 * v1.w;
      acc[3][0][0] += p3 * v0.x; acc[3][0][1] += p3 * v0.y; acc[3][0][2] += p3 * v0.z; acc[3][0][3] += p3 * v0.w;
      acc[3][1][0] += p3 * v1.x; acc[3][1][1] += p3 * v1.y; acc[3][1][2] += p3 * v1.z; acc[3][1][3] += p3 * v1.w;
      acc[4][0][0] += p4 * v0.x; acc[4][0][1] += p4 * v0.y; acc[4][0][2] += p4 * v0.z; acc[4][0][3] += p4 * v0.w;
      acc[4][1][0] += p4 * v1.x; acc[4][1][1] += p4 * v1.y; acc[4][1][2] += p4 * v1.z; acc[4][1][3] += p4 * v1.w;
      acc[5][0][0] += p5 * v0.x; acc[5][0][1] += p5 * v0.y; acc[5][0][2] += p5 * v0.z; acc[5][0][3] += p5 * v0.w;
      acc[5][1][0] += p5 * v1.x; acc[5][1][1] += p5 * v1.y; acc[5][1][2] += p5 * v1.z; acc[5][1][3] += p5 * v1.w;
      acc[6][0][0] += p6 * v0.x; acc[6][0][1] += p6 * v0.y; acc[6][0][2] += p6 * v0.z; acc[6][0][3] += p6 * v0.w;
      acc[6][1][0] += p6 * v1.x; acc[6][1][1] += p6 * v1.y; acc[6][1][2] += p6 * v1.z; acc[6][1][3] += p6 * v1.w;
      acc[7][0][0] += p7 * v0.x; acc[7][0][1] += p7 * v0.y; acc[7][0][2] += p7 * v0.z; acc[7][0][3] += p7 * v0.w;
      acc[7][1][0] += p7 * v1.x; acc[7][1][1] += p7 * v1.y; acc[7][1][2] += p7 * v1.z; acc[7][1][3] += p7 * v1.w;
    }
    __syncthreads();
  }
#pragma unroll
  for (int i = 0; i < 8; ++i) {
    const int t = t0 + i;
    const float inv = 1.f / den[(((size_t)b * T_ + t) * U_ + ty) * H_ + h];
    const size_t rbase = ((size_t)b * TU_ + (size_t)t * U_ + ty) * D_ + h * DH_;
    float4 o0, o1;
    o0.x = acc[i][0][0] * inv; o0.y = acc[i][0][1] * inv; o0.z = acc[i][0][2] * inv; o0.w = acc[i][0][3] * inv;
    o1.x = acc[i][1][0] * inv; o1.y = acc[i][1][1] * inv; o1.z = acc[i][1][2] * inv; o1.w = acc[i][1][3] * inv;
    *(float4*)&aout[rbase + tx * 4] = o0;
    *(float4*)&aout[rbase + 64 + tx * 4] = o1;
  }
}

// ---------------- decode scan helpers ----------------
__global__ __launch_bounds__(256) void k_bits(
    const float* __restrict__ prob, const int* __restrict__ hidx,
    unsigned char* __restrict__ bits) {
  int i = blockIdx.x * 256 + threadIdx.x;
  if (i >= B_ * T_ * U_) return;
  int u = i & 15, bt = i >> 4, b = bt >> 7;
  int valid = (u + 1 < U_ - 1) ? (u + 1) : (U_ - 1);
  int tok = hidx[b * U_ + valid];
  size_t base = (size_t)i * C_;
  bits[i] = (prob[base + tok] > prob[base]) ? 1 : 0;
}

__global__ __launch_bounds__(64) void k_scan(
    const unsigned char* __restrict__ bits, int* __restrict__ u_sel) {
  __shared__ unsigned char sb[B_ * T_ * U_];
  int tid = threadIdx.x;
  for (int i = tid; i < B_ * T_ * U_; i += 64) sb[i] = bits[i];
  __syncthreads();
  if (tid < B_) {
    int u = 0;
    for (int t = 0; t < T_; ++t) {
      int uc = (u < U_ - 1) ? u : (U_ - 1);
      u_sel[tid * T_ + t] = uc;
      u = uc + (int)sb[(tid * T_ + t) * U_ + uc];
    }
  }
}

__global__ __launch_bounds__(128) void k_gather_o(
    const float* __restrict__ out_final, const int* __restrict__ u_sel,
    float* __restrict__ o) {
  int bt = blockIdx.x;
  int uc = u_sel[bt];
  const float4* src = (const float4*)(out_final + ((size_t)bt * U_ + uc) * D_);
  float4* dst = (float4*)(o + (size_t)bt * D_);
  dst[threadIdx.x] = src[threadIdx.x];
}

// ---------------- host launch ----------------
extern "C" void kernel_launch(void* const* d_in, const int* in_sizes, int n_in,
                              void* d_out, int out_size, void* d_ws, size_t ws_size,
                              hipStream_t stream) {
  const float* model_embed = (const float*)d_in[0];
  const float* emb_table   = (const float*)d_in[1];
  const float* Wih_f = (const float*)d_in[2];
  const float* Whh_f = (const float*)d_in[3];
  const float* b_f   = (const float*)d_in[4];
  const float* Wih_b = (const float*)d_in[5];
  const float* Whh_b = (const float*)d_in[6];
  const float* b_b   = (const float*)d_in[7];
  const float* ctx_out_W  = (const float*)d_in[8];
  const float* hist_Wih   = (const float*)d_in[9];
  const float* hist_Whh   = (const float*)d_in[10];
  const float* hist_b     = (const float*)d_in[11];
  const float* hist_out_W = (const float*)d_in[12];
  const float* Wq = (const float*)d_in[13];
  const float* Wk = (const float*)d_in[14];
  const float* Wv = (const float*)d_in[15];
  const float* Wo = (const float*)d_in[16];
  const float* acoustic_W = (const float*)d_in[17];
  const int* ctx_idxs = (const int*)d_in[18];
  const int* hidx     = (const int*)d_in[19];
  const int* ilens    = (const int*)d_in[20];

  if (ws_size < WS_NEED * sizeof(float)) return;

  float* ws = (float*)d_ws;
  float* o_out     = (float*)d_out;
  float* logit_out = o_out + (size_t)B_ * T_ * D_;
  float* prob_out  = logit_out + (size_t)B_ * T_ * U_ * C_;

  // zero: h_ping + c_state (adjacent), hist c-state
  hipMemsetAsync(ws + HPING, 0, 4ul * C_ * E_ * sizeof(float), stream);
  hipMemsetAsync(ws + HISTC, 0, (size_t)B_ * D_ * sizeof(float), stream);

  // ---- weight folding: Wqa = Wq @ acoustic_W, Wqh = Wq @ hist_out_W ----
  k_gemm_nn<<<dim3(8, 8, 2), 256, 0, stream>>>(
      Wq, acoustic_W, ws + WQA, Wq, hist_out_W, ws + WQH);

  // ---- ctx LSTM input projections, all (dir,t) at once ----
  {
    GemmP p{};
    p.A1 = emb_table; p.lda1 = E_;
    p.ridx = ctx_idxs; p.gmode = 1;
    p.W1 = Wih_f; p.W1b = Wih_b; p.ldw1 = E_;
    p.bias = b_f; p.biasb = b_b;
    p.out = ws + XZ_; p.ldc = E4_;
    p.M = 2 * CL_; p.N = E4_; p.K = E_; p.scale = 1.f;
    k_gemm128<<<dim3(8, 250, 1), 256, 0, stream>>>(p);
  }

  // ---- ctx LSTM recurrence: 8 fused steps (GEMM + gates) ----
  for (int t = 0; t < L_; ++t) {
    float* hp = ws + ((t & 1) ? HPONG : HPING);
    float* hn = ws + ((t & 1) ? HPING : HPONG);
    k_ctx_step<<<dim3(4, 32, 2), 256, 0, stream>>>(
        ws + XZ_, Whh_f, Whh_b, hp, hn, ws + CST,
        ws + HFALL, ws + HBALL, t);
  }

  // ---- masked mean + ctx_out projection ----
  k_ctx_mean<<<dim3((C_ * 2 * E_ + 255) / 256), 256, 0, stream>>>(
      ws + HFALL, ws + HBALL, ilens, ws + CATM);
  {
    GemmP p{};
    p.A1 = ws + CATM; p.lda1 = 2 * E_;
    p.W1 = ctx_out_W; p.ldw1 = 2 * E_;
    p.out = ws + CTXM; p.ldc = D_; p.M = C_; p.N = D_; p.K = 2 * E_; p.scale = 1.f;
    k_gemm64<<<dim3(8, 16, 1), 256, 0, stream>>>(p);
  }

  // ---- k (scaled) and v ----
  {
    GemmP pk{};
    pk.A1 = ws + CTXM; pk.lda1 = D_;
    pk.W1 = Wk; pk.ldw1 = D_;
    pk.out = ws + KWS; pk.ldc = D_; pk.M = C_; pk.N = D_; pk.K = D_; pk.scale = SCALE_;
    GemmP pv = pk;
    pv.W1 = Wv; pv.out = ws + VWS; pv.scale = 1.f;
    k_gemm64x2<<<dim3(8, 16, 2), 256, 0, stream>>>(pk, pv, 1);
  }

  // ---- hist LSTM input projection (gathered rows) ----
  {
    GemmP p{};
    p.A1 = ws + CTXM; p.lda1 = D_;
    p.ridx = hidx; p.ridx_stride = 1; p.ridx_off = 0;
    p.W1 = hist_Wih; p.ldw1 = D_;
    p.bias = hist_b;
    p.out = ws + HXP; p.ldc = D4_; p.M = B_ * U_; p.N = D4_; p.K = D_; p.scale = 1.f;
    k_gemm64<<<dim3(32, 2, 1), 256, 0, stream>>>(p);
  }

  // ---- hist LSTM recurrence ----
  for (int u = 0; u < U_; ++u) {
    k_hist_step<<<dim3(64), 64, 0, stream>>>(ws + HXP, hist_Whh, ws + HALL, ws + HISTC, u);
  }

  // ---- qm = model_embed @ Wqa^T ; qh = hall @ Wqh^T ----
  {
    GemmP pm{};
    pm.A1 = model_embed; pm.lda1 = D_;
    pm.W1 = ws + WQA; pm.ldw1 = D_;
    pm.out = ws + QM_; pm.ldc = D_; pm.M = B_ * T_; pm.N = D_; pm.K = D_; pm.scale = 1.f;
    GemmP ph = pm;
    ph.A1 = ws + HALL; ph.W1 = ws + WQH; ph.out = ws + QH_; ph.M = B_ * U_;
    k_gemm64x2<<<dim3(8, 16, 2), 256, 0, stream>>>(pm, ph, 1);
  }

  // ---- Sm, Sh (per-head via z) ----
  {
    GemmP pm{};
    pm.A1 = ws + QM_; pm.lda1 = D_;
    pm.W1 = ws + KWS; pm.ldw1 = D_;
    pm.out = ws + SM_; pm.ldc = HC_; pm.M = B_ * T_; pm.N = C_; pm.K = DH_; pm.scale = 1.f;
    pm.a_zoff = DH_; pm.w_zoff = DH_; pm.c_zoff = C_;
    GemmP ph = pm;
    ph.A1 = ws + QH_; ph.out = ws + SH_; ph.M = B_ * U_;
    k_gemm64x2<<<dim3(16, 16, 8), 256, 0, stream>>>(pm, ph, 4);
  }

  // ---- exp factorization + outputs ----
  k_rowexp<<<dim3(B_ * T_ + B_ * U_), 256, 0, stream>>>(
      ws + SM_, ws + SH_, ws + SMSUM, ws + SHSUM);
  k_problogit<<<dim3(B_ * T_), 256, 0, stream>>>(
      ws + SM_, ws + SH_, ws + SMSUM, ws + SHSUM, ws + DEN_, prob_out, logit_out);

  // ---- PV ----
  k_pv<<<dim3(16, B_ * H_), 256, 0, stream>>>(
      ws + SM_, ws + SH_, ws + DEN_, ws + VWS, ws + AOUT_);

  // ---- Wo projection ----
  {
    GemmP p{};
    p.A1 = ws + AOUT_; p.lda1 = D_;
    p.W1 = Wo; p.ldw1 = D_;
    p.out = ws + OFIN_; p.ldc = D_; p.M = B_ * TU_; p.N = D_; p.K = D_; p.scale = 1.f;
    k_gemm128<<<dim3(4, 256, 1), 256, 0, stream>>>(p);
  }

  // ---- decode ----
  k_bits<<<dim3(64), 256, 0, stream>>>(prob_out, hidx, (unsigned char*)(ws + BITS_));
  k_scan<<<dim3(1), 64, 0, stream>>>((const unsigned char*)(ws + BITS_), (int*)(ws + USEL_));
  k_gather_o<<<dim3(B_ * T_), 128, 0, stream>>>(ws + OFIN_, (const int*)(ws + USEL_), o_out);
}

// Round 4
// 1701.834 us; speedup vs baseline: 1.7931x; 1.1473x over previous
//
#include <hip/hip_runtime.h>
#include <math.h>

// ---------------- compile-time sizes ----------------
namespace {
constexpr int B_ = 8, T_ = 128, D_ = 512, C_ = 1000, L_ = 8, U_ = 16, E_ = 256, H_ = 4;
constexpr int VOC_ = 5000;
constexpr int DH_ = D_ / H_;      // 128
constexpr int E4_ = 4 * E_;       // 1024
constexpr int D4_ = 4 * D_;       // 2048
constexpr int TU_ = T_ * U_;      // 2048
constexpr int HC_ = H_ * C_;      // 4000
constexpr float SCALE_ = 0.088388347648318447f; // 1/sqrt(128)

// ---------------- ws layout (float offsets) ----------------
// REGION A: XZ (2*5000*1024 = 10.24M, dead after ctx steps) aliases SM/SH/AOUT
constexpr size_t XZ_    = 0;
constexpr size_t SM_    = 0;                                   // B*T*H*C = 4,096,000
constexpr size_t SH_    = SM_ + (size_t)B_ * T_ * HC_;         // B*U*H*C = 512,000
constexpr size_t AOUT_  = SH_ + (size_t)B_ * U_ * HC_;         // B*T*D = 524,288
constexpr size_t REG_A  = 2ul * VOC_ * E4_;                    // 10,240,000 (> 5.14M)
constexpr size_t HPING  = REG_A;                               // 2*C*E
constexpr size_t CST    = HPING + 2ul * C_ * E_;               // 2*C*E (adjacent: one memset)
constexpr size_t HPONG  = CST + 2ul * C_ * E_;
constexpr size_t HFALL  = HPONG + 2ul * C_ * E_;               // C*L*E
constexpr size_t HBALL  = HFALL + (size_t)C_ * L_ * E_;
constexpr size_t CATM   = HBALL + (size_t)C_ * L_ * E_;        // C*2E
constexpr size_t CTXM   = CATM + (size_t)C_ * 2 * E_;          // C*D
constexpr size_t KWS    = CTXM + (size_t)C_ * D_;
constexpr size_t VWS    = KWS + (size_t)C_ * D_;
constexpr size_t WQA    = VWS + (size_t)C_ * D_;               // D*D
constexpr size_t WQH    = WQA + (size_t)D_ * D_;               // D*D
constexpr size_t HXP    = WQH + (size_t)D_ * D_;               // B*U*4D
constexpr size_t HALL   = HXP + (size_t)B_ * U_ * D4_;         // B*U*D
constexpr size_t HISTC  = HALL + (size_t)B_ * U_ * D_;         // B*D
constexpr size_t QM_    = HISTC + (size_t)B_ * D_;             // B*T*D
constexpr size_t QH_    = QM_ + (size_t)B_ * T_ * D_;          // B*U*D
constexpr size_t SMSUM  = QH_ + (size_t)B_ * U_ * D_;          // B*T*C
constexpr size_t SHSUM  = SMSUM + (size_t)B_ * T_ * C_;        // B*U*C
constexpr size_t DEN_   = SHSUM + (size_t)B_ * U_ * C_;        // B*T*U*H
constexpr size_t BITS_  = DEN_ + (size_t)B_ * T_ * U_ * H_;    // 16384 B
constexpr size_t USEL_  = BITS_ + 4096;
constexpr size_t WS_NEED = USEL_ + (size_t)B_ * T_;
} // namespace

__device__ __forceinline__ float fsig(float x)  { return 1.f / (1.f + __expf(-x)); }
__device__ __forceinline__ float ftanh(float x) { return 1.f - 2.f / (__expf(2.f * x) + 1.f); }
__device__ __forceinline__ void fma4(float4& a, float w, const float4& v) {
  a.x += w * v.x; a.y += w * v.y; a.z += w * v.z; a.w += w * v.w;
}

// ---------------- generic NT GEMM (X @ W^T) ----------------
struct GemmP {
  const float* A1; int lda1;
  const int* ridx; int ridx_stride; int ridx_off;  // optional row gather on A1
  const float* W1; int ldw1;
  const float* bias;
  float* out; int ldc;
  int M, N, K;
  float scale;
  int a_zoff, w_zoff, c_zoff;
};

template <int TN>
__device__ __forceinline__ void gemm_core(const GemmP& g, int z) {
  constexpr int UN = TN / 16;
  __shared__ float As[16][68];
  __shared__ float Ws[16][TN + 4];
  const int m0 = blockIdx.y * 64;
  const int n0 = blockIdx.x * TN;
  if (m0 >= g.M || n0 >= g.N) return;
  const float* A1 = g.A1 + (long)z * g.a_zoff;
  const float* W1 = g.W1 + (long)z * g.w_zoff;
  float* out = g.out + (long)z * g.c_zoff;
  const int tid = threadIdx.x;
  const int lk = tid & 15, lr = tid >> 4;
  const int tx = tid & 15, ty = tid >> 4;
  float acc[4][UN] = {};
  int arow[4];
#pragma unroll
  for (int p = 0; p < 4; ++p) {
    const int gm = m0 + lr + p * 16;
    if (gm >= g.M) { arow[p] = -1; continue; }
    arow[p] = g.ridx ? g.ridx[gm * g.ridx_stride + g.ridx_off] : gm;
  }
  for (int k0 = 0; k0 < g.K; k0 += 16) {
    const int kk = k0 + lk;
#pragma unroll
    for (int p = 0; p < 4; ++p) {
      const int r = lr + p * 16;
      As[lk][r] = (arow[p] >= 0) ? A1[(long)arow[p] * g.lda1 + kk] : 0.f;
    }
#pragma unroll
    for (int p = 0; p < UN; ++p) {
      const int r = lr + p * 16;
      const int gn = n0 + r;
      Ws[lk][r] = (gn < g.N) ? W1[(long)gn * g.ldw1 + kk] : 0.f;
    }
    __syncthreads();
#pragma unroll
    for (int k = 0; k < 16; ++k) {
      const float4 a = *(const float4*)&As[k][ty * 4];
#pragma unroll
      for (int q = 0; q < UN / 4; ++q) {
        const float4 w = *(const float4*)&Ws[k][q * 64 + tx * 4];
        acc[0][q*4+0] += a.x * w.x; acc[0][q*4+1] += a.x * w.y; acc[0][q*4+2] += a.x * w.z; acc[0][q*4+3] += a.x * w.w;
        acc[1][q*4+0] += a.y * w.x; acc[1][q*4+1] += a.y * w.y; acc[1][q*4+2] += a.y * w.z; acc[1][q*4+3] += a.y * w.w;
        acc[2][q*4+0] += a.z * w.x; acc[2][q*4+1] += a.z * w.y; acc[2][q*4+2] += a.z * w.z; acc[2][q*4+3] += a.z * w.w;
        acc[3][q*4+0] += a.w * w.x; acc[3][q*4+1] += a.w * w.y; acc[3][q*4+2] += a.w * w.z; acc[3][q*4+3] += a.w * w.w;
      }
    }
    __syncthreads();
  }
#pragma unroll
  for (int i = 0; i < 4; ++i) {
    const int gm = m0 + ty * 4 + i;
    if (gm >= g.M) continue;
#pragma unroll
    for (int q = 0; q < UN / 4; ++q) {
#pragma unroll
      for (int j = 0; j < 4; ++j) {
        const int gn = n0 + q * 64 + tx * 4 + j;
        if (gn >= g.N) continue;
        float v2 = acc[i][q*4+j];
        if (g.bias) v2 += g.bias[gn];
        out[(long)gm * g.ldc + gn] = v2 * g.scale;
      }
    }
  }
}

__global__ __launch_bounds__(256) void k_gemm64(GemmP p)  { gemm_core<64>(p, blockIdx.z); }
__global__ __launch_bounds__(256) void k_gemm64x2(GemmP p0, GemmP p1, int zs) {
  int z = blockIdx.z;
  if (z < zs) gemm_core<64>(p0, z); else gemm_core<64>(p1, z - zs);
}
__global__ __launch_bounds__(256) void k_gemm64x3(GemmP p0, GemmP p1, GemmP p2) {
  int z = blockIdx.z;
  if (z == 0) gemm_core<64>(p0, 0);
  else if (z == 1) gemm_core<64>(p1, 0);
  else gemm_core<64>(p2, 0);
}
__global__ __launch_bounds__(256) void k_gemm128x2(GemmP p0, GemmP p1, int zs) {
  int z = blockIdx.z;
  if (z < zs) gemm_core<128>(p0, z); else gemm_core<128>(p1, z - zs);
}

// ---------------- NN GEMM: O = A @ B, 512x512x512 (weight folding) ----------------
__global__ __launch_bounds__(256) void k_gemm_nn(
    const float* __restrict__ A0, const float* __restrict__ B0, float* __restrict__ O0,
    const float* __restrict__ A1, const float* __restrict__ B1, float* __restrict__ O1) {
  const float* A = blockIdx.z ? A1 : A0;
  const float* B = blockIdx.z ? B1 : B0;
  float* O = blockIdx.z ? O1 : O0;
  __shared__ float As[16][68];
  __shared__ float Bs[16][68];
  const int m0 = blockIdx.y * 64, n0 = blockIdx.x * 64;
  const int tid = threadIdx.x;
  const int lk = tid & 15, lr = tid >> 4;
  const int tx = tid & 15, ty = tid >> 4;
  float acc[4][4] = {};
  for (int k0 = 0; k0 < 512; k0 += 16) {
#pragma unroll
    for (int p = 0; p < 4; ++p) {
      const int r = lr + p * 16;
      As[lk][r] = A[(long)(m0 + r) * 512 + k0 + lk];
    }
#pragma unroll
    for (int p = 0; p < 4; ++p) {
      int idx = tid + p * 256;
      int kk = idx >> 6, jj = idx & 63;
      Bs[kk][jj] = B[(long)(k0 + kk) * 512 + n0 + jj];
    }
    __syncthreads();
#pragma unroll
    for (int k = 0; k < 16; ++k) {
      const float4 a = *(const float4*)&As[k][ty * 4];
      const float4 w = *(const float4*)&Bs[k][tx * 4];
      acc[0][0] += a.x * w.x; acc[0][1] += a.x * w.y; acc[0][2] += a.x * w.z; acc[0][3] += a.x * w.w;
      acc[1][0] += a.y * w.x; acc[1][1] += a.y * w.y; acc[1][2] += a.y * w.z; acc[1][3] += a.y * w.w;
      acc[2][0] += a.z * w.x; acc[2][1] += a.z * w.y; acc[2][2] += a.z * w.z; acc[2][3] += a.z * w.w;
      acc[3][0] += a.w * w.x; acc[3][1] += a.w * w.y; acc[3][2] += a.w * w.z; acc[3][3] += a.w * w.w;
    }
    __syncthreads();
  }
#pragma unroll
  for (int i = 0; i < 4; ++i)
#pragma unroll
    for (int j = 0; j < 4; ++j)
      O[(long)(m0 + ty * 4 + i) * 512 + n0 + tx * 4 + j] = acc[i][j];
}

// ---------------- ctx LSTM recurrent step: z = XZ[tok] + h@Whh^T, gates fused ----------------
// grid (4 etiles, 32 ctiles, 2 dirs); 256 thr; block = 32c x 64e x 4 gates, K=256
__global__ __launch_bounds__(256) void k_ctx_step(
    const float* __restrict__ xz, const int* __restrict__ ctx_idxs,
    const float* __restrict__ Whh_f, const float* __restrict__ Whh_b,
    const float* __restrict__ h_prev, float* __restrict__ h_next,
    float* __restrict__ c_st,
    float* __restrict__ hf_all, float* __restrict__ hb_all, int t) {
  __shared__ float Hs[16][36];
  __shared__ float Wg[4][16][68];
  const int e0 = blockIdx.x * 64;
  const int c0 = blockIdx.y * 32;
  const int dir = blockIdx.z;
  const int tid = threadIdx.x;
  const float* Whh = dir ? Whh_b : Whh_f;
  const float* hp = h_prev + (size_t)dir * C_ * E_;
  const int cy = tid >> 4, ex = tid & 15;
  float acc[4][2][4] = {};
  for (int k0 = 0; k0 < E_; k0 += 16) {
    {
      int idx = tid;
#pragma unroll
      for (int p = 0; p < 2; ++p, idx += 256) {
        int kk = idx & 15, cr = idx >> 4;
        int c = c0 + cr;
        Hs[kk][cr] = (c < C_) ? hp[(size_t)c * E_ + k0 + kk] : 0.f;
      }
    }
    {
      int idx = tid;
#pragma unroll
      for (int p = 0; p < 16; ++p, idx += 256) {
        int kk = idx & 15, rest = idx >> 4;
        int ee = rest & 63, gg = rest >> 6;
        Wg[gg][kk][ee] = Whh[(size_t)(gg * E_ + e0 + ee) * E_ + k0 + kk];
      }
    }
    __syncthreads();
#pragma unroll
    for (int kk = 0; kk < 16; ++kk) {
      const float a0 = Hs[kk][cy * 2];
      const float a1 = Hs[kk][cy * 2 + 1];
#pragma unroll
      for (int gg = 0; gg < 4; ++gg) {
        const float4 w = *(const float4*)&Wg[gg][kk][ex * 4];
        acc[gg][0][0] += a0 * w.x; acc[gg][0][1] += a0 * w.y; acc[gg][0][2] += a0 * w.z; acc[gg][0][3] += a0 * w.w;
        acc[gg][1][0] += a1 * w.x; acc[gg][1][1] += a1 * w.y; acc[gg][1][2] += a1 * w.z; acc[gg][1][3] += a1 * w.w;
      }
    }
    __syncthreads();
  }
  const int lpos = dir ? (L_ - 1 - t) : t;
  const float* xz_dir = xz + (size_t)dir * VOC_ * E4_;
  float* c_state = c_st + (size_t)dir * C_ * E_;
  float* hn_out = h_next + (size_t)dir * C_ * E_;
  float* hall = dir ? hb_all : hf_all;
#pragma unroll
  for (int i = 0; i < 2; ++i) {
    const int c = c0 + cy * 2 + i;
    if (c >= C_) continue;
    const int e = e0 + ex * 4;
    const int tok = ctx_idxs[c * L_ + lpos];
    const float* xr = xz_dir + (size_t)tok * E4_;
    float zi[4], zf[4], zg[4], zo[4], cp[4], cn[4], hn[4];
    *(float4*)zi = *(const float4*)&xr[e];
    *(float4*)zf = *(const float4*)&xr[E_ + e];
    *(float4*)zg = *(const float4*)&xr[2 * E_ + e];
    *(float4*)zo = *(const float4*)&xr[3 * E_ + e];
    *(float4*)cp = *(const float4*)&c_state[(size_t)c * E_ + e];
#pragma unroll
    for (int j = 0; j < 4; ++j) {
      float vi = zi[j] + acc[0][i][j];
      float vf = zf[j] + acc[1][i][j];
      float vg = zg[j] + acc[2][i][j];
      float vo = zo[j] + acc[3][i][j];
      cn[j] = fsig(vf) * cp[j] + fsig(vi) * ftanh(vg);
      hn[j] = fsig(vo) * ftanh(cn[j]);
    }
    *(float4*)&c_state[(size_t)c * E_ + e] = *(float4*)cn;
    *(float4*)&hn_out[(size_t)c * E_ + e] = *(float4*)hn;
    *(float4*)&hall[((size_t)c * L_ + lpos) * E_ + e] = *(float4*)hn;
  }
}

// ---------------- masked mean over L of concat(hf,hb) ----------------
__global__ __launch_bounds__(256) void k_ctx_mean(
    const float* __restrict__ hf_all, const float* __restrict__ hb_all,
    const int* __restrict__ ilens, float* __restrict__ cat_mean) {
  int idx = blockIdx.x * 256 + threadIdx.x;
  if (idx >= C_ * 2 * E_) return;
  int c = idx / (2 * E_), e = idx - c * 2 * E_;
  const float* src = (e < E_) ? hf_all : hb_all;
  int ee = e & (E_ - 1);
  int il = ilens[c];
  float s = 0.f;
#pragma unroll
  for (int l = 0; l < L_; ++l)
    if (l < il) s += src[((size_t)c * L_ + l) * E_ + ee];
  cat_mean[idx] = s / (float)il;
}

// ---------------- hist LSTM: one step ----------------
__global__ __launch_bounds__(64) void k_hist_step(
    const float* __restrict__ xproj, const float* __restrict__ Whh,
    float* __restrict__ hall, float* __restrict__ c_st, int u) {
  __shared__ float hs[B_ * D_];
  int tid = threadIdx.x;
  for (int i = tid; i < B_ * D_; i += 64) {
    int bb = i >> 9, ee = i & 511;
    hs[i] = (u == 0) ? 0.f : hall[((size_t)bb * U_ + (u - 1)) * D_ + ee];
  }
  __syncthreads();
  int g = blockIdx.x * 64 + tid;
  int b = g >> 9, e = g & 511;
  const float* xp = xproj + ((size_t)b * U_ + u) * D4_;
  float zi = xp[e], zf = xp[e + D_], zg = xp[e + 2 * D_], zo = xp[e + 3 * D_];
  const float4* w0 = (const float4*)(Whh + (size_t)e * D_);
  const float4* w1 = (const float4*)(Whh + (size_t)(e + D_) * D_);
  const float4* w2 = (const float4*)(Whh + (size_t)(e + 2 * D_) * D_);
  const float4* w3 = (const float4*)(Whh + (size_t)(e + 3 * D_) * D_);
  const float4* hv = (const float4*)(hs + (size_t)b * D_);
#pragma unroll 4
  for (int k = 0; k < D_ / 4; ++k) {
    float4 h4 = hv[k];
    float4 a = w0[k]; zi += a.x * h4.x + a.y * h4.y + a.z * h4.z + a.w * h4.w;
    float4 bb4 = w1[k]; zf += bb4.x * h4.x + bb4.y * h4.y + bb4.z * h4.z + bb4.w * h4.w;
    float4 cc4 = w2[k]; zg += cc4.x * h4.x + cc4.y * h4.y + cc4.z * h4.z + cc4.w * h4.w;
    float4 dd4 = w3[k]; zo += dd4.x * h4.x + dd4.y * h4.y + dd4.z * h4.z + dd4.w * h4.w;
  }
  float cn = fsig(zf) * c_st[g] + fsig(zi) * ftanh(zg);
  c_st[g] = cn;
  hall[((size_t)b * U_ + u) * D_ + e] = fsig(zo) * ftanh(cn);
}

// ---------------- row-wise exp: Sm->EM / Sh->EH in place (+ head-sums) ----------------
__global__ __launch_bounds__(256) void k_rowexp(
    float* __restrict__ Sm, float* __restrict__ Sh,
    float* __restrict__ SmS, float* __restrict__ ShS) {
  int row = blockIdx.x;
  float* base; float* sumo;
  if (row < B_ * T_) { base = Sm + (size_t)row * HC_; sumo = SmS + (size_t)row * C_; }
  else { int r2 = row - B_ * T_; base = Sh + (size_t)r2 * HC_; sumo = ShS + (size_t)r2 * C_; }
  int tid = threadIdx.x;
  for (int c = tid; c < C_; c += 256) {
    float s = base[c] + base[C_ + c] + base[2 * C_ + c] + base[3 * C_ + c];
    sumo[c] = 0.25f * s;
  }
  __syncthreads();
  int h = tid >> 6, lane = tid & 63;
  float* p = base + (size_t)h * C_;
  float mx = -1e30f;
  for (int c = lane; c < C_; c += 64) mx = fmaxf(mx, p[c]);
#pragma unroll
  for (int o = 32; o; o >>= 1) mx = fmaxf(mx, __shfl_xor(mx, o));
  for (int c = lane; c < C_; c += 64) p[c] = __expf(p[c] - mx);
}

// ---------------- prob/logit outputs + denominators ----------------
__global__ __launch_bounds__(256) void k_problogit(
    const float* __restrict__ EM, const float* __restrict__ EH,
    const float* __restrict__ SmS, const float* __restrict__ ShS,
    float* __restrict__ den, float* __restrict__ prob, float* __restrict__ logit) {
  __shared__ float sEM[H_][1008];
  __shared__ float sSS[1000];
  __shared__ float sInv[H_];
  int bt = blockIdx.x;
  int b = bt >> 7;
  int tid = threadIdx.x;
  for (int i = tid; i < H_ * C_; i += 256) sEM[i / C_][i % C_] = EM[(size_t)bt * HC_ + i];
  for (int c = tid; c < C_; c += 256) sSS[c] = SmS[(size_t)bt * C_ + c];
  __syncthreads();
  int h = tid >> 6, lane = tid & 63;
  for (int u = 0; u < U_; ++u) {
    const float* ehp = EH + (((size_t)b * U_ + u) * H_ + h) * C_;
    float s = 0.f;
    for (int c = lane; c < C_; c += 64) s += sEM[h][c] * ehp[c];
#pragma unroll
    for (int o = 32; o; o >>= 1) s += __shfl_xor(s, o);
    if (lane == 0) {
      sInv[h] = 1.f / s;
      den[((size_t)bt * U_ + u) * H_ + h] = s;
    }
    __syncthreads();
    const float i0 = sInv[0] * 0.25f, i1 = sInv[1] * 0.25f;
    const float i2 = sInv[2] * 0.25f, i3 = sInv[3] * 0.25f;
    const float* eh0 = EH + ((size_t)b * U_ + u) * HC_;
    const float* shs = ShS + ((size_t)b * U_ + u) * C_;
    size_t obase = ((size_t)bt * U_ + u) * C_;
    for (int c = tid; c < C_; c += 256) {
      float pr = sEM[0][c] * eh0[c] * i0 + sEM[1][c] * eh0[C_ + c] * i1
               + sEM[2][c] * eh0[2 * C_ + c] * i2 + sEM[3][c] * eh0[3 * C_ + c] * i3;
      prob[obase + c] = pr;
      logit[obase + c] = sSS[c] + shs[c];
    }
    __syncthreads();
  }
}

// ---------------- decode scan helpers ----------------
__global__ __launch_bounds__(256) void k_bits(
    const float* __restrict__ prob, const int* __restrict__ hidx,
    unsigned char* __restrict__ bits) {
  int i = blockIdx.x * 256 + threadIdx.x;
  if (i >= B_ * T_ * U_) return;
  int u = i & 15, bt = i >> 4, b = bt >> 7;
  int valid = (u + 1 < U_ - 1) ? (u + 1) : (U_ - 1);
  int tok = hidx[b * U_ + valid];
  size_t base = (size_t)i * C_;
  bits[i] = (prob[base + tok] > prob[base]) ? 1 : 0;
}

__global__ __launch_bounds__(64) void k_scan(
    const unsigned char* __restrict__ bits, int* __restrict__ u_sel) {
  __shared__ unsigned char sb[B_ * T_ * U_];
  int tid = threadIdx.x;
  for (int i = tid; i < B_ * T_ * U_; i += 64) sb[i] = bits[i];
  __syncthreads();
  if (tid < B_) {
    int u = 0;
    for (int t = 0; t < T_; ++t) {
      int uc = (u < U_ - 1) ? u : (U_ - 1);
      u_sel[tid * T_ + t] = uc;
      u = uc + (int)sb[(tid * T_ + t) * U_ + uc];
    }
  }
}

// ---------------- PV on SELECTED rows only ----------------
// grid 128 blocks; 8 rows/block (2 subgroups x 4); 256 thr; thread -> 4 d-cols
__global__ __launch_bounds__(256) void k_pvg(
    const float* __restrict__ EM, const float* __restrict__ EH,
    const float* __restrict__ den, const int* __restrict__ u_sel,
    const float* __restrict__ vmat, float* __restrict__ aout) {
  constexpr int KC = 64;
  __shared__ float wS[2][4][4][KC + 4];   // [sub][g][h][cc]
  __shared__ float invS[8][4];
  __shared__ int bS[8], tS[8], uS[8];
  const int tid = threadIdx.x;
  if (tid < 32) {
    int g8 = tid >> 2, hh = tid & 3;
    int bt = blockIdx.x * 8 + g8;
    int b = bt >> 7, t = bt & 127;
    int u = u_sel[bt];
    if (hh == 0) { bS[g8] = b; tS[g8] = t; uS[g8] = u; }
    invS[g8][hh] = 1.f / den[((size_t)bt * U_ + u) * H_ + hh];
  }
  __syncthreads();
  const int sub = tid >> 7, lt = tid & 127;
  const int d = lt * 4;
  const int h = lt >> 5;
  float4 acc[4];
  acc[0] = acc[1] = acc[2] = acc[3] = make_float4(0.f, 0.f, 0.f, 0.f);
  for (int c0 = 0; c0 < C_; c0 += KC) {
#pragma unroll
    for (int p = 0; p < 8; ++p) {
      int idx = tid + p * 256;
      int cc = idx & 63;
      int rest = idx >> 6;
      int hh = rest & 3, gg = (rest >> 2) & 3, ss = rest >> 4;
      int g8 = ss * 4 + gg;
      int c = c0 + cc;
      float w = 0.f;
      if (c < C_) {
        int b = bS[g8], t = tS[g8], u = uS[g8];
        float em = EM[(((size_t)b * T_ + t) * H_ + hh) * C_ + c];
        float eh = EH[(((size_t)b * U_ + u) * H_ + hh) * C_ + c];
        w = em * eh * invS[g8][hh];
      }
      wS[ss][gg][hh][cc] = w;
    }
    __syncthreads();
#pragma unroll 4
    for (int q = 0; q < KC / 4; ++q) {
      const float4 w0 = *(const float4*)&wS[sub][0][h][q * 4];
      const float4 w1 = *(const float4*)&wS[sub][1][h][q * 4];
      const float4 w2 = *(const float4*)&wS[sub][2][h][q * 4];
      const float4 w3 = *(const float4*)&wS[sub][3][h][q * 4];
      int c = c0 + q * 4;
      float4 v;
      if (c < C_) { v = *(const float4*)&vmat[(size_t)c * D_ + d];
        fma4(acc[0], w0.x, v); fma4(acc[1], w1.x, v); fma4(acc[2], w2.x, v); fma4(acc[3], w3.x, v); }
      if (c + 1 < C_) { v = *(const float4*)&vmat[(size_t)(c + 1) * D_ + d];
        fma4(acc[0], w0.y, v); fma4(acc[1], w1.y, v); fma4(acc[2], w2.y, v); fma4(acc[3], w3.y, v); }
      if (c + 2 < C_) { v = *(const float4*)&vmat[(size_t)(c + 2) * D_ + d];
        fma4(acc[0], w0.z, v); fma4(acc[1], w1.z, v); fma4(acc[2], w2.z, v); fma4(acc[3], w3.z, v); }
      if (c + 3 < C_) { v = *(const float4*)&vmat[(size_t)(c + 3) * D_ + d];
        fma4(acc[0], w0.w, v); fma4(acc[1], w1.w, v); fma4(acc[2], w2.w, v); fma4(acc[3], w3.w, v); }
    }
    __syncthreads();
  }
#pragma unroll
  for (int g = 0; g < 4; ++g) {
    int bt = (bS[sub * 4 + g] << 7) + tS[sub * 4 + g];
    *(float4*)&aout[(size_t)bt * D_ + d] = acc[g];
  }
}

// ---------------- host launch ----------------
extern "C" void kernel_launch(void* const* d_in, const int* in_sizes, int n_in,
                              void* d_out, int out_size, void* d_ws, size_t ws_size,
                              hipStream_t stream) {
  const float* model_embed = (const float*)d_in[0];
  const float* emb_table   = (const float*)d_in[1];
  const float* Wih_f = (const float*)d_in[2];
  const float* Whh_f = (const float*)d_in[3];
  const float* b_f   = (const float*)d_in[4];
  const float* Wih_b = (const float*)d_in[5];
  const float* Whh_b = (const float*)d_in[6];
  const float* b_b   = (const float*)d_in[7];
  const float* ctx_out_W  = (const float*)d_in[8];
  const float* hist_Wih   = (const float*)d_in[9];
  const float* hist_Whh   = (const float*)d_in[10];
  const float* hist_b     = (const float*)d_in[11];
  const float* hist_out_W = (const float*)d_in[12];
  const float* Wq = (const float*)d_in[13];
  const float* Wk = (const float*)d_in[14];
  const float* Wv = (const float*)d_in[15];
  const float* Wo = (const float*)d_in[16];
  const float* acoustic_W = (const float*)d_in[17];
  const int* ctx_idxs = (const int*)d_in[18];
  const int* hidx     = (const int*)d_in[19];
  const int* ilens    = (const int*)d_in[20];

  if (ws_size < WS_NEED * sizeof(float)) return;

  float* ws = (float*)d_ws;
  float* o_out     = (float*)d_out;
  float* logit_out = o_out + (size_t)B_ * T_ * D_;
  float* prob_out  = logit_out + (size_t)B_ * T_ * U_ * C_;

  // zero: ctx h_ping + c_state (adjacent), hist c-state
  hipMemsetAsync(ws + HPING, 0, 4ul * C_ * E_ * sizeof(float), stream);
  hipMemsetAsync(ws + HISTC, 0, (size_t)B_ * D_ * sizeof(float), stream);

  // ---- weight folding: Wqa = Wq @ acoustic_W, Wqh = Wq @ hist_out_W ----
  k_gemm_nn<<<dim3(8, 8, 2), 256, 0, stream>>>(
      Wq, acoustic_W, ws + WQA, Wq, hist_out_W, ws + WQH);

  // ---- ctx LSTM input projections for the WHOLE VOCAB (both dirs) ----
  {
    GemmP pf{};
    pf.A1 = emb_table; pf.lda1 = E_;
    pf.W1 = Wih_f; pf.ldw1 = E_;
    pf.bias = b_f;
    pf.out = ws + XZ_; pf.ldc = E4_;
    pf.M = VOC_; pf.N = E4_; pf.K = E_; pf.scale = 1.f;
    GemmP pb = pf;
    pb.W1 = Wih_b; pb.bias = b_b; pb.out = ws + XZ_ + (size_t)VOC_ * E4_;
    k_gemm128x2<<<dim3(8, (VOC_ + 63) / 64, 2), 256, 0, stream>>>(pf, pb, 1);
  }

  // ---- ctx LSTM recurrence: 8 fused steps (GEMM + token-gather + gates) ----
  for (int t = 0; t < L_; ++t) {
    float* hp = ws + ((t & 1) ? HPONG : HPING);
    float* hn = ws + ((t & 1) ? HPING : HPONG);
    k_ctx_step<<<dim3(4, 32, 2), 256, 0, stream>>>(
        ws + XZ_, ctx_idxs, Whh_f, Whh_b, hp, hn, ws + CST,
        ws + HFALL, ws + HBALL, t);
  }

  // ---- masked mean + ctx_out projection ----
  k_ctx_mean<<<dim3((C_ * 2 * E_ + 255) / 256), 256, 0, stream>>>(
      ws + HFALL, ws + HBALL, ilens, ws + CATM);
  {
    GemmP p{};
    p.A1 = ws + CATM; p.lda1 = 2 * E_;
    p.W1 = ctx_out_W; p.ldw1 = 2 * E_;
    p.out = ws + CTXM; p.ldc = D_; p.M = C_; p.N = D_; p.K = 2 * E_; p.scale = 1.f;
    k_gemm64<<<dim3(8, 16, 1), 256, 0, stream>>>(p);
  }

  // ---- k (scaled), v, hist input projection — one launch ----
  {
    GemmP pk{};
    pk.A1 = ws + CTXM; pk.lda1 = D_;
    pk.W1 = Wk; pk.ldw1 = D_;
    pk.out = ws + KWS; pk.ldc = D_; pk.M = C_; pk.N = D_; pk.K = D_; pk.scale = SCALE_;
    GemmP pv = pk;
    pv.W1 = Wv; pv.out = ws + VWS; pv.scale = 1.f;
    GemmP ph{};
    ph.A1 = ws + CTXM; ph.lda1 = D_;
    ph.ridx = hidx; ph.ridx_stride = 1; ph.ridx_off = 0;
    ph.W1 = hist_Wih; ph.ldw1 = D_;
    ph.bias = hist_b;
    ph.out = ws + HXP; ph.ldc = D4_; ph.M = B_ * U_; ph.N = D4_; ph.K = D_; ph.scale = 1.f;
    k_gemm64x3<<<dim3(32, 16, 3), 256, 0, stream>>>(pk, pv, ph);
  }

  // ---- hist LSTM recurrence ----
  for (int u = 0; u < U_; ++u) {
    k_hist_step<<<dim3(64), 64, 0, stream>>>(ws + HXP, hist_Whh, ws + HALL, ws + HISTC, u);
  }

  // ---- qm = model_embed @ Wqa^T ; qh = hall @ Wqh^T ----
  {
    GemmP pm{};
    pm.A1 = model_embed; pm.lda1 = D_;
    pm.W1 = ws + WQA; pm.ldw1 = D_;
    pm.out = ws + QM_; pm.ldc = D_; pm.M = B_ * T_; pm.N = D_; pm.K = D_; pm.scale = 1.f;
    GemmP ph = pm;
    ph.A1 = ws + HALL; ph.W1 = ws + WQH; ph.out = ws + QH_; ph.M = B_ * U_;
    k_gemm64x2<<<dim3(8, 16, 2), 256, 0, stream>>>(pm, ph, 1);
  }

  // ---- Sm, Sh (per-head via z) ----
  {
    GemmP pm{};
    pm.A1 = ws + QM_; pm.lda1 = D_;
    pm.W1 = ws + KWS; pm.ldw1 = D_;
    pm.out = ws + SM_; pm.ldc = HC_; pm.M = B_ * T_; pm.N = C_; pm.K = DH_; pm.scale = 1.f;
    pm.a_zoff = DH_; pm.w_zoff = DH_; pm.c_zoff = C_;
    GemmP ph = pm;
    ph.A1 = ws + QH_; ph.out = ws + SH_; ph.M = B_ * U_;
    k_gemm64x2<<<dim3(16, 16, 8), 256, 0, stream>>>(pm, ph, 4);
  }

  // ---- exp factorization + outputs ----
  k_rowexp<<<dim3(B_ * T_ + B_ * U_), 256, 0, stream>>>(
      ws + SM_, ws + SH_, ws + SMSUM, ws + SHSUM);
  k_problogit<<<dim3(B_ * T_), 256, 0, stream>>>(
      ws + SM_, ws + SH_, ws + SMSUM, ws + SHSUM, ws + DEN_, prob_out, logit_out);

  // ---- decode BEFORE PV: u_sel from prob ----
  k_bits<<<dim3(64), 256, 0, stream>>>(prob_out, hidx, (unsigned char*)(ws + BITS_));
  k_scan<<<dim3(1), 64, 0, stream>>>((const unsigned char*)(ws + BITS_), (int*)(ws + USEL_));

  // ---- PV on the 1024 selected rows only ----
  k_pvg<<<dim3(128), 256, 0, stream>>>(
      ws + SM_, ws + SH_, ws + DEN_, (const int*)(ws + USEL_), ws + VWS, ws + AOUT_);

  // ---- Wo projection on selected rows -> o (direct to output) ----
  {
    GemmP p{};
    p.A1 = ws + AOUT_; p.lda1 = D_;
    p.W1 = Wo; p.ldw1 = D_;
    p.out = o_out; p.ldc = D_; p.M = B_ * T_; p.N = D_; p.K = D_; p.scale = 1.f;
    k_gemm64<<<dim3(8, 16, 1), 256, 0, stream>>>(p);
  }
}

// Round 5
// 1286.054 us; speedup vs baseline: 2.3729x; 1.3233x over previous
//
#include <hip/hip_runtime.h>
#include <math.h>

// ---------------- compile-time sizes ----------------
namespace {
constexpr int B_ = 8, T_ = 128, D_ = 512, C_ = 1000, L_ = 8, U_ = 16, E_ = 256, H_ = 4;
constexpr int VOC_ = 5000;
constexpr int DH_ = D_ / H_;      // 128
constexpr int E4_ = 4 * E_;       // 1024
constexpr int D4_ = 4 * D_;       // 2048
constexpr int TU_ = T_ * U_;      // 2048
constexpr int HC_ = H_ * C_;      // 4000
constexpr float SCALE_ = 0.088388347648318447f; // 1/sqrt(128)

// ---------------- ws layout (float offsets) ----------------
// REGION A: XZ (2*5000*1024 = 10.24M, dead after ctx steps) aliases SM/SH/AOUT
constexpr size_t XZ_    = 0;
constexpr size_t SM_    = 0;                                   // B*T*H*C = 4,096,000
constexpr size_t SH_    = SM_ + (size_t)B_ * T_ * HC_;         // B*U*H*C = 512,000
constexpr size_t AOUT_  = SH_ + (size_t)B_ * U_ * HC_;         // B*T*D = 524,288
constexpr size_t REG_A  = 2ul * VOC_ * E4_;                    // 10,240,000
constexpr size_t HPING  = REG_A;                               // 2*C*E
constexpr size_t CST    = HPING + 2ul * C_ * E_;               // 2*C*E (adjacent: one memset)
constexpr size_t HPONG  = CST + 2ul * C_ * E_;
constexpr size_t HFALL  = HPONG + 2ul * C_ * E_;               // C*L*E
constexpr size_t HBALL  = HFALL + (size_t)C_ * L_ * E_;
constexpr size_t CATM   = HBALL + (size_t)C_ * L_ * E_;        // C*2E
constexpr size_t CTXM   = CATM + (size_t)C_ * 2 * E_;          // C*D
constexpr size_t KWS    = CTXM + (size_t)C_ * D_;
constexpr size_t VWS    = KWS + (size_t)C_ * D_;
constexpr size_t WQA    = VWS + (size_t)C_ * D_;               // D*D
constexpr size_t WQH    = WQA + (size_t)D_ * D_;               // D*D
constexpr size_t HXP    = WQH + (size_t)D_ * D_;               // B*U*4D
constexpr size_t HALL   = HXP + (size_t)B_ * U_ * D4_;         // B*U*D
constexpr size_t HGLOB  = HALL + (size_t)B_ * U_ * D_;         // B*D
constexpr size_t QM_    = HGLOB + (size_t)B_ * D_;             // B*T*D
constexpr size_t QH_    = QM_ + (size_t)B_ * T_ * D_;          // B*U*D
constexpr size_t SMSUM  = QH_ + (size_t)B_ * U_ * D_;          // B*T*C
constexpr size_t SHSUM  = SMSUM + (size_t)B_ * T_ * C_;        // B*U*C
constexpr size_t DEN_   = SHSUM + (size_t)B_ * U_ * C_;        // B*T*U*H
constexpr size_t BITS_  = DEN_ + (size_t)B_ * T_ * U_ * H_;    // 16384 B
constexpr size_t USEL_  = BITS_ + 4096;
constexpr size_t BAR_   = USEL_ + (size_t)B_ * T_;             // 2 ints
constexpr size_t WS_NEED = BAR_ + 16;
} // namespace

__device__ __forceinline__ float fsig(float x)  { return 1.f / (1.f + __expf(-x)); }
__device__ __forceinline__ float ftanh(float x) { return 1.f - 2.f / (__expf(2.f * x) + 1.f); }
__device__ __forceinline__ void fma4(float4& a, float w, const float4& v) {
  a.x += w * v.x; a.y += w * v.y; a.z += w * v.z; a.w += w * v.w;
}

// ---------------- generic NT GEMM (X @ W^T), 64 x TN tile, float4 staging ----------------
struct GemmP {
  const float* A1; int lda1;
  const int* ridx; int ridx_stride; int ridx_off;  // optional row gather on A1
  const float* W1; int ldw1;
  const float* bias;
  float* out; int ldc;
  int M, N, K;
  float scale;
  int a_zoff, w_zoff, c_zoff;
};

template <int TN>
__device__ __forceinline__ void gemm_core(const GemmP& g, int z) {
  constexpr int UN = TN / 16;
  __shared__ float As[16][68];
  __shared__ float Ws[16][TN + 4];
  const int m0 = blockIdx.y * 64;
  const int n0 = blockIdx.x * TN;
  if (m0 >= g.M || n0 >= g.N) return;
  const float* A1 = g.A1 + (long)z * g.a_zoff;
  const float* W1 = g.W1 + (long)z * g.w_zoff;
  float* out = g.out + (long)z * g.c_zoff;
  const int tid = threadIdx.x;
  const int tx = tid & 15, ty = tid >> 4;
  const int sr = tid >> 2, skq = (tid & 3) * 4;
  float acc[4][UN] = {};
  int sarow = -1;
  {
    const int gm = m0 + sr;
    if (gm < g.M) sarow = g.ridx ? g.ridx[gm * g.ridx_stride + g.ridx_off] : gm;
  }
  for (int k0 = 0; k0 < g.K; k0 += 16) {
    {
      float4 v = make_float4(0.f, 0.f, 0.f, 0.f);
      if (sarow >= 0) v = *(const float4*)&A1[(long)sarow * g.lda1 + k0 + skq];
      As[skq][sr] = v.x; As[skq + 1][sr] = v.y; As[skq + 2][sr] = v.z; As[skq + 3][sr] = v.w;
    }
#pragma unroll
    for (int p = 0; p < TN / 64; ++p) {
      const int r = sr + p * 64;
      const int gn = n0 + r;
      float4 w = make_float4(0.f, 0.f, 0.f, 0.f);
      if (gn < g.N) w = *(const float4*)&W1[(long)gn * g.ldw1 + k0 + skq];
      Ws[skq][r] = w.x; Ws[skq + 1][r] = w.y; Ws[skq + 2][r] = w.z; Ws[skq + 3][r] = w.w;
    }
    __syncthreads();
#pragma unroll
    for (int k = 0; k < 16; ++k) {
      const float4 a = *(const float4*)&As[k][ty * 4];
#pragma unroll
      for (int q = 0; q < UN / 4; ++q) {
        const float4 w = *(const float4*)&Ws[k][q * 64 + tx * 4];
        acc[0][q*4+0] += a.x * w.x; acc[0][q*4+1] += a.x * w.y; acc[0][q*4+2] += a.x * w.z; acc[0][q*4+3] += a.x * w.w;
        acc[1][q*4+0] += a.y * w.x; acc[1][q*4+1] += a.y * w.y; acc[1][q*4+2] += a.y * w.z; acc[1][q*4+3] += a.y * w.w;
        acc[2][q*4+0] += a.z * w.x; acc[2][q*4+1] += a.z * w.y; acc[2][q*4+2] += a.z * w.z; acc[2][q*4+3] += a.z * w.w;
        acc[3][q*4+0] += a.w * w.x; acc[3][q*4+1] += a.w * w.y; acc[3][q*4+2] += a.w * w.z; acc[3][q*4+3] += a.w * w.w;
      }
    }
    __syncthreads();
  }
#pragma unroll
  for (int i = 0; i < 4; ++i) {
    const int gm = m0 + ty * 4 + i;
    if (gm >= g.M) continue;
#pragma unroll
    for (int q = 0; q < UN / 4; ++q) {
#pragma unroll
      for (int j = 0; j < 4; ++j) {
        const int gn = n0 + q * 64 + tx * 4 + j;
        if (gn >= g.N) continue;
        float v2 = acc[i][q*4+j];
        if (g.bias) v2 += g.bias[gn];
        out[(long)gm * g.ldc + gn] = v2 * g.scale;
      }
    }
  }
}

__global__ __launch_bounds__(256) void k_gemm64(GemmP p)  { gemm_core<64>(p, blockIdx.z); }
__global__ __launch_bounds__(256) void k_gemm64x2(GemmP p0, GemmP p1, int zs) {
  int z = blockIdx.z;
  if (z < zs) gemm_core<64>(p0, z); else gemm_core<64>(p1, z - zs);
}
__global__ __launch_bounds__(256) void k_gemm64x3(GemmP p0, GemmP p1, GemmP p2) {
  int z = blockIdx.z;
  if (z == 0) gemm_core<64>(p0, 0);
  else if (z == 1) gemm_core<64>(p1, 0);
  else gemm_core<64>(p2, 0);
}

// ---------------- big NT GEMM: 128x128 tile, micro 8x8, float4 staging ----------------
struct GemmB {
  const float* A; int lda;
  const float* W; int ldw;
  const float* bias;
  float* out; int ldc;
  int M, N, K;
  float scale;
  int a_zoff, w_zoff, c_zoff;
};

__device__ __forceinline__ void gemm_big_core(const GemmB& g, int z) {
  __shared__ float As[16][132];
  __shared__ float Ws[16][132];
  const int m0 = blockIdx.y * 128;
  const int n0 = blockIdx.x * 128;
  if (m0 >= g.M || n0 >= g.N) return;
  const float* A = g.A + (long)z * g.a_zoff;
  const float* W = g.W + (long)z * g.w_zoff;
  float* out = g.out + (long)z * g.c_zoff;
  const int tid = threadIdx.x;
  const int tx = tid & 15, ty = tid >> 4;
  const int sr = tid >> 2, skq = (tid & 3) * 4;
  float4 acc[2][2][4];
#pragma unroll
  for (int a = 0; a < 2; ++a)
#pragma unroll
    for (int b2 = 0; b2 < 2; ++b2)
#pragma unroll
      for (int i = 0; i < 4; ++i) acc[a][b2][i] = make_float4(0.f, 0.f, 0.f, 0.f);
  for (int k0 = 0; k0 < g.K; k0 += 16) {
#pragma unroll
    for (int p = 0; p < 2; ++p) {
      const int r = sr + p * 64;
      const int gm = m0 + r;
      float4 v = make_float4(0.f, 0.f, 0.f, 0.f);
      if (gm < g.M) v = *(const float4*)&A[(long)gm * g.lda + k0 + skq];
      As[skq][r] = v.x; As[skq + 1][r] = v.y; As[skq + 2][r] = v.z; As[skq + 3][r] = v.w;
      const int gn = n0 + r;
      float4 w = make_float4(0.f, 0.f, 0.f, 0.f);
      if (gn < g.N) w = *(const float4*)&W[(long)gn * g.ldw + k0 + skq];
      Ws[skq][r] = w.x; Ws[skq + 1][r] = w.y; Ws[skq + 2][r] = w.z; Ws[skq + 3][r] = w.w;
    }
    __syncthreads();
#pragma unroll
    for (int k = 0; k < 16; ++k) {
      const float4 a0 = *(const float4*)&As[k][ty * 4];
      const float4 a1 = *(const float4*)&As[k][64 + ty * 4];
      const float4 w0 = *(const float4*)&Ws[k][tx * 4];
      const float4 w1 = *(const float4*)&Ws[k][64 + tx * 4];
      fma4(acc[0][0][0], a0.x, w0); fma4(acc[0][0][1], a0.y, w0); fma4(acc[0][0][2], a0.z, w0); fma4(acc[0][0][3], a0.w, w0);
      fma4(acc[0][1][0], a0.x, w1); fma4(acc[0][1][1], a0.y, w1); fma4(acc[0][1][2], a0.z, w1); fma4(acc[0][1][3], a0.w, w1);
      fma4(acc[1][0][0], a1.x, w0); fma4(acc[1][0][1], a1.y, w0); fma4(acc[1][0][2], a1.z, w0); fma4(acc[1][0][3], a1.w, w0);
      fma4(acc[1][1][0], a1.x, w1); fma4(acc[1][1][1], a1.y, w1); fma4(acc[1][1][2], a1.z, w1); fma4(acc[1][1][3], a1.w, w1);
    }
    __syncthreads();
  }
#pragma unroll
  for (int a = 0; a < 2; ++a) {
#pragma unroll
    for (int i = 0; i < 4; ++i) {
      const int gm = m0 + a * 64 + ty * 4 + i;
      if (gm >= g.M) continue;
#pragma unroll
      for (int b2 = 0; b2 < 2; ++b2) {
        const int gn = n0 + b2 * 64 + tx * 4;
        if (gn >= g.N) continue;
        float4 v = acc[a][b2][i];
        if (g.bias) {
          v.x += g.bias[gn]; v.y += g.bias[gn + 1]; v.z += g.bias[gn + 2]; v.w += g.bias[gn + 3];
        }
        v.x *= g.scale; v.y *= g.scale; v.z *= g.scale; v.w *= g.scale;
        if (gn + 3 < g.N) {
          *(float4*)&out[(long)gm * g.ldc + gn] = v;
        } else {
          float vv[4] = {v.x, v.y, v.z, v.w};
          for (int j = 0; j < 4; ++j) if (gn + j < g.N) out[(long)gm * g.ldc + gn + j] = vv[j];
        }
      }
    }
  }
}

__global__ __launch_bounds__(256) void k_gemm_bigx2(GemmB p0, GemmB p1, int zs) {
  int z = blockIdx.z;
  if (z < zs) gemm_big_core(p0, z); else gemm_big_core(p1, z - zs);
}

// ---------------- NN GEMM: O = A @ B, 512x512x512 (weight folding) ----------------
__global__ __launch_bounds__(256) void k_gemm_nn(
    const float* __restrict__ A0, const float* __restrict__ B0, float* __restrict__ O0,
    const float* __restrict__ A1, const float* __restrict__ B1, float* __restrict__ O1) {
  const float* A = blockIdx.z ? A1 : A0;
  const float* B = blockIdx.z ? B1 : B0;
  float* O = blockIdx.z ? O1 : O0;
  __shared__ float As[16][68];
  __shared__ float Bs[16][68];
  const int m0 = blockIdx.y * 64, n0 = blockIdx.x * 64;
  const int tid = threadIdx.x;
  const int tx = tid & 15, ty = tid >> 4;
  const int sr = tid >> 2, skq = (tid & 3) * 4;
  float acc[4][4] = {};
  for (int k0 = 0; k0 < 512; k0 += 16) {
    {
      float4 v = *(const float4*)&A[(long)(m0 + sr) * 512 + k0 + skq];
      As[skq][sr] = v.x; As[skq + 1][sr] = v.y; As[skq + 2][sr] = v.z; As[skq + 3][sr] = v.w;
    }
#pragma unroll
    for (int p = 0; p < 4; ++p) {
      int idx = tid + p * 256;
      int kk = idx >> 6, jj = idx & 63;
      Bs[kk][jj] = B[(long)(k0 + kk) * 512 + n0 + jj];
    }
    __syncthreads();
#pragma unroll
    for (int k = 0; k < 16; ++k) {
      const float4 a = *(const float4*)&As[k][ty * 4];
      const float4 w = *(const float4*)&Bs[k][tx * 4];
      acc[0][0] += a.x * w.x; acc[0][1] += a.x * w.y; acc[0][2] += a.x * w.z; acc[0][3] += a.x * w.w;
      acc[1][0] += a.y * w.x; acc[1][1] += a.y * w.y; acc[1][2] += a.y * w.z; acc[1][3] += a.y * w.w;
      acc[2][0] += a.z * w.x; acc[2][1] += a.z * w.y; acc[2][2] += a.z * w.z; acc[2][3] += a.z * w.w;
      acc[3][0] += a.w * w.x; acc[3][1] += a.w * w.y; acc[3][2] += a.w * w.z; acc[3][3] += a.w * w.w;
    }
    __syncthreads();
  }
#pragma unroll
  for (int i = 0; i < 4; ++i)
#pragma unroll
    for (int j = 0; j < 4; ++j)
      O[(long)(m0 + ty * 4 + i) * 512 + n0 + tx * 4 + j] = acc[i][j];
}

// ---------------- ctx LSTM recurrent step: z = XZ[tok] + h@Whh^T, gates fused ----------------
// grid (4 etiles, 32 ctiles, 2 dirs); 256 thr; BK=32; float4 staging
__global__ __launch_bounds__(256) void k_ctx_step(
    const float* __restrict__ xz, const int* __restrict__ ctx_idxs,
    const float* __restrict__ Whh_f, const float* __restrict__ Whh_b,
    const float* __restrict__ h_prev, float* __restrict__ h_next,
    float* __restrict__ c_st,
    float* __restrict__ hf_all, float* __restrict__ hb_all, int t) {
  __shared__ float Hs[32][36];
  __shared__ float Wg[4][32][68];
  const int e0 = blockIdx.x * 64;
  const int c0 = blockIdx.y * 32;
  const int dir = blockIdx.z;
  const int tid = threadIdx.x;
  const float* Whh = dir ? Whh_b : Whh_f;
  const float* hp = h_prev + (size_t)dir * C_ * E_;
  const int cy = tid >> 4, ex = tid & 15;
  float acc[4][2][4] = {};
  for (int k0 = 0; k0 < E_; k0 += 32) {
    {
      int cr = tid & 31, kq = (tid >> 5) * 4;
      int c = c0 + cr;
      float4 v = make_float4(0.f, 0.f, 0.f, 0.f);
      if (c < C_) v = *(const float4*)&hp[(size_t)c * E_ + k0 + kq];
      Hs[kq][cr] = v.x; Hs[kq + 1][cr] = v.y; Hs[kq + 2][cr] = v.z; Hs[kq + 3][cr] = v.w;
    }
#pragma unroll
    for (int p = 0; p < 8; ++p) {
      int idx = tid + p * 256;
      int ee = idx & 63, kq = ((idx >> 6) & 7) * 4, gg = idx >> 9;
      float4 v = *(const float4*)&Whh[(size_t)(gg * E_ + e0 + ee) * E_ + k0 + kq];
      Wg[gg][kq][ee] = v.x; Wg[gg][kq + 1][ee] = v.y; Wg[gg][kq + 2][ee] = v.z; Wg[gg][kq + 3][ee] = v.w;
    }
    __syncthreads();
#pragma unroll
    for (int kk = 0; kk < 32; ++kk) {
      const float a0 = Hs[kk][cy * 2];
      const float a1 = Hs[kk][cy * 2 + 1];
#pragma unroll
      for (int gg = 0; gg < 4; ++gg) {
        const float4 w = *(const float4*)&Wg[gg][kk][ex * 4];
        acc[gg][0][0] += a0 * w.x; acc[gg][0][1] += a0 * w.y; acc[gg][0][2] += a0 * w.z; acc[gg][0][3] += a0 * w.w;
        acc[gg][1][0] += a1 * w.x; acc[gg][1][1] += a1 * w.y; acc[gg][1][2] += a1 * w.z; acc[gg][1][3] += a1 * w.w;
      }
    }
    __syncthreads();
  }
  const int lpos = dir ? (L_ - 1 - t) : t;
  const float* xz_dir = xz + (size_t)dir * VOC_ * E4_;
  float* c_state = c_st + (size_t)dir * C_ * E_;
  float* hn_out = h_next + (size_t)dir * C_ * E_;
  float* hall = dir ? hb_all : hf_all;
#pragma unroll
  for (int i = 0; i < 2; ++i) {
    const int c = c0 + cy * 2 + i;
    if (c >= C_) continue;
    const int e = e0 + ex * 4;
    const int tok = ctx_idxs[c * L_ + lpos];
    const float* xr = xz_dir + (size_t)tok * E4_;
    float zi[4], zf[4], zg[4], zo[4], cp[4], cn[4], hn[4];
    *(float4*)zi = *(const float4*)&xr[e];
    *(float4*)zf = *(const float4*)&xr[E_ + e];
    *(float4*)zg = *(const float4*)&xr[2 * E_ + e];
    *(float4*)zo = *(const float4*)&xr[3 * E_ + e];
    *(float4*)cp = *(const float4*)&c_state[(size_t)c * E_ + e];
#pragma unroll
    for (int j = 0; j < 4; ++j) {
      float vi = zi[j] + acc[0][i][j];
      float vf = zf[j] + acc[1][i][j];
      float vg = zg[j] + acc[2][i][j];
      float vo = zo[j] + acc[3][i][j];
      cn[j] = fsig(vf) * cp[j] + fsig(vi) * ftanh(vg);
      hn[j] = fsig(vo) * ftanh(cn[j]);
    }
    *(float4*)&c_state[(size_t)c * E_ + e] = *(float4*)cn;
    *(float4*)&hn_out[(size_t)c * E_ + e] = *(float4*)hn;
    *(float4*)&hall[((size_t)c * L_ + lpos) * E_ + e] = *(float4*)hn;
  }
}

// ---------------- masked mean over L of concat(hf,hb) ----------------
__global__ __launch_bounds__(256) void k_ctx_mean(
    const float* __restrict__ hf_all, const float* __restrict__ hb_all,
    const int* __restrict__ ilens, float* __restrict__ cat_mean) {
  int idx = blockIdx.x * 256 + threadIdx.x;
  if (idx >= C_ * 2 * E_) return;
  int c = idx / (2 * E_), e = idx - c * 2 * E_;
  const float* src = (e < E_) ? hf_all : hb_all;
  int ee = e & (E_ - 1);
  int il = ilens[c];
  float s = 0.f;
#pragma unroll
  for (int l = 0; l < L_; ++l)
    if (l < il) s += src[((size_t)c * L_ + l) * E_ + ee];
  cat_mean[idx] = s / (float)il;
}

// ---------------- persistent hist LSTM: all 16 steps, Whh in LDS, grid barrier ----------------
// 256 blocks x 256 thr; block = (eslice of 8) x (b-pair of 2); c-state in registers
__global__ __launch_bounds__(256) void k_hist_fused(
    const float* __restrict__ xproj, const float* __restrict__ Whh,
    float* __restrict__ hall, float* __restrict__ hglob,
    int* __restrict__ bar_cnt, int* __restrict__ bar_sense) {
  __shared__ float Wl[4][8][516];
  __shared__ float hbuf[2][520];
  const int tid = threadIdx.x;
  const int es = blockIdx.x >> 2;
  const int b0 = (blockIdx.x & 3) * 2;
  // ---- load weight slice once: 4 gates x 8 e x 512 k = 64 KB ----
#pragma unroll
  for (int p = 0; p < 16; ++p) {
    int f4 = tid + p * 256;
    int k4 = f4 & 127;
    int rem2 = f4 >> 7;
    int e2 = rem2 & 7, g2 = rem2 >> 3;
    float4 v = *(const float4*)&Whh[((size_t)(g2 * D_ + es * 8 + e2)) * D_ + k4 * 4];
    *(float4*)&Wl[g2][e2][k4 * 4] = v;
  }
  const int o = tid >> 2, ks = tid & 3;
  const int bb = o >> 5, orem = o & 31, e = orem >> 2, g = orem & 3;
  const int l0 = (tid & 63) & 48;
  const int isLead = ((tid & 15) == 0);
  const int lb = b0 + (tid >> 7);
  const int le = (tid >> 4) & 7;
  float cstate = 0.f;
  for (int u = 0; u < U_; ++u) {
    // ---- stage h (device-scope loads; zeros at u=0) ----
#pragma unroll
    for (int p = 0; p < 4; ++p) {
      int idx = tid + p * 256;
      int bb2 = idx >> 9, k = idx & 511;
      float hv = 0.f;
      if (u > 0)
        hv = __hip_atomic_load(&hglob[(b0 + bb2) * D_ + k], __ATOMIC_RELAXED, __HIP_MEMORY_SCOPE_AGENT);
      hbuf[bb2][k] = hv;
    }
    __syncthreads();
    // ---- dot: this thread's k-slice (interleaved by ks) ----
    float dot = 0.f;
#pragma unroll
    for (int j = 0; j < 32; ++j) {
      int k4 = j * 4 + ks;
      float4 wv = *(const float4*)&Wl[g][e][k4 * 4];
      float4 hv = *(const float4*)&hbuf[bb][k4 * 4];
      dot += wv.x * hv.x + wv.y * hv.y + wv.z * hv.z + wv.w * hv.w;
    }
    dot += __shfl_xor(dot, 1);
    dot += __shfl_xor(dot, 2);
    float z = 0.f;
    if (ks == 0)
      z = dot + xproj[((size_t)(b0 + bb) * U_ + u) * D4_ + g * D_ + es * 8 + e];
    float zi = __shfl(z, l0 + 0, 64);
    float zf = __shfl(z, l0 + 4, 64);
    float zg = __shfl(z, l0 + 8, 64);
    float zo = __shfl(z, l0 + 12, 64);
    if (isLead) {
      cstate = fsig(zf) * cstate + fsig(zi) * ftanh(zg);
      float hv = fsig(zo) * ftanh(cstate);
      __hip_atomic_store(&hglob[lb * D_ + es * 8 + le], hv, __ATOMIC_RELAXED, __HIP_MEMORY_SCOPE_AGENT);
      hall[((size_t)lb * U_ + u) * D_ + es * 8 + le] = hv;
    }
    if (u < U_ - 1) {
      __threadfence();
      __syncthreads();
      if (tid == 0) {
        const int want = (u + 1) & 1;
        if (atomicAdd(bar_cnt, 1) == (int)gridDim.x - 1) {
          __hip_atomic_store(bar_cnt, 0, __ATOMIC_RELAXED, __HIP_MEMORY_SCOPE_AGENT);
          __hip_atomic_store(bar_sense, want, __ATOMIC_RELEASE, __HIP_MEMORY_SCOPE_AGENT);
        } else {
          while (__hip_atomic_load(bar_sense, __ATOMIC_ACQUIRE, __HIP_MEMORY_SCOPE_AGENT) != want)
            __builtin_amdgcn_s_sleep(1);
        }
      }
      __syncthreads();
    }
  }
}

// ---------------- row-wise exp: Sm->EM / Sh->EH in place (+ head-sums) ----------------
__global__ __launch_bounds__(256) void k_rowexp(
    float* __restrict__ Sm, float* __restrict__ Sh,
    float* __restrict__ SmS, float* __restrict__ ShS) {
  int row = blockIdx.x;
  float* base; float* sumo;
  if (row < B_ * T_) { base = Sm + (size_t)row * HC_; sumo = SmS + (size_t)row * C_; }
  else { int r2 = row - B_ * T_; base = Sh + (size_t)r2 * HC_; sumo = ShS + (size_t)r2 * C_; }
  int tid = threadIdx.x;
  for (int c = tid; c < C_; c += 256) {
    float s = base[c] + base[C_ + c] + base[2 * C_ + c] + base[3 * C_ + c];
    sumo[c] = 0.25f * s;
  }
  __syncthreads();
  int h = tid >> 6, lane = tid & 63;
  float* p = base + (size_t)h * C_;
  float mx = -1e30f;
  for (int c = lane; c < C_; c += 64) mx = fmaxf(mx, p[c]);
#pragma unroll
  for (int o = 32; o; o >>= 1) mx = fmaxf(mx, __shfl_xor(mx, o));
  for (int c = lane; c < C_; c += 64) p[c] = __expf(p[c] - mx);
}

// ---------------- prob/logit outputs + denominators + decode bits ----------------
__global__ __launch_bounds__(256) void k_problogit(
    const float* __restrict__ EM, const float* __restrict__ EH,
    const float* __restrict__ SmS, const float* __restrict__ ShS,
    const int* __restrict__ hidx,
    float* __restrict__ den, float* __restrict__ prob, float* __restrict__ logit,
    unsigned char* __restrict__ bits) {
  __shared__ float sEM[H_][1008];
  __shared__ float sSS[1000];
  __shared__ float sInv[H_];
  __shared__ float sB, sT;
  int bt = blockIdx.x;
  int b = bt >> 7;
  int tid = threadIdx.x;
  for (int i = tid; i < H_ * C_; i += 256) sEM[i / C_][i % C_] = EM[(size_t)bt * HC_ + i];
  for (int c = tid; c < C_; c += 256) sSS[c] = SmS[(size_t)bt * C_ + c];
  __syncthreads();
  int h = tid >> 6, lane = tid & 63;
  for (int u = 0; u < U_; ++u) {
    const int valid = (u + 1 < U_ - 1) ? (u + 1) : (U_ - 1);
    const int tok = hidx[b * U_ + valid];
    const float* ehp = EH + (((size_t)b * U_ + u) * H_ + h) * C_;
    float s = 0.f;
    for (int c = lane; c < C_; c += 64) s += sEM[h][c] * ehp[c];
#pragma unroll
    for (int o = 32; o; o >>= 1) s += __shfl_xor(s, o);
    if (lane == 0) {
      sInv[h] = 1.f / s;
      den[((size_t)bt * U_ + u) * H_ + h] = s;
    }
    __syncthreads();
    const float i0 = sInv[0] * 0.25f, i1 = sInv[1] * 0.25f;
    const float i2 = sInv[2] * 0.25f, i3 = sInv[3] * 0.25f;
    const float* eh0 = EH + ((size_t)b * U_ + u) * HC_;
    const float* shs = ShS + ((size_t)b * U_ + u) * C_;
    size_t obase = ((size_t)bt * U_ + u) * C_;
    for (int c = tid; c < C_; c += 256) {
      float pr = sEM[0][c] * eh0[c] * i0 + sEM[1][c] * eh0[C_ + c] * i1
               + sEM[2][c] * eh0[2 * C_ + c] * i2 + sEM[3][c] * eh0[3 * C_ + c] * i3;
      prob[obase + c] = pr;
      logit[obase + c] = sSS[c] + shs[c];
      if (c == 0) sB = pr;
      if (c == tok) sT = pr;
    }
    __syncthreads();
    if (tid == 0) bits[bt * U_ + u] = (sT > sB) ? 1 : 0;
  }
}

// ---------------- decode scan ----------------
__global__ __launch_bounds__(64) void k_scan(
    const unsigned char* __restrict__ bits, int* __restrict__ u_sel) {
  __shared__ unsigned char sb[B_ * T_ * U_];
  int tid = threadIdx.x;
  for (int i = tid; i < B_ * T_ * U_; i += 64) sb[i] = bits[i];
  __syncthreads();
  if (tid < B_) {
    int u = 0;
    for (int t = 0; t < T_; ++t) {
      int uc = (u < U_ - 1) ? u : (U_ - 1);
      u_sel[tid * T_ + t] = uc;
      u = uc + (int)sb[(tid * T_ + t) * U_ + uc];
    }
  }
}

// ---------------- PV on SELECTED rows only ----------------
__global__ __launch_bounds__(256) void k_pvg(
    const float* __restrict__ EM, const float* __restrict__ EH,
    const float* __restrict__ den, const int* __restrict__ u_sel,
    const float* __restrict__ vmat, float* __restrict__ aout) {
  constexpr int KC = 64;
  __shared__ float wS[2][4][4][KC + 4];   // [sub][g][h][cc]
  __shared__ float invS[8][4];
  __shared__ int bS[8], tS[8], uS[8];
  const int tid = threadIdx.x;
  if (tid < 32) {
    int g8 = tid >> 2, hh = tid & 3;
    int bt = blockIdx.x * 8 + g8;
    int b = bt >> 7, t = bt & 127;
    int u = u_sel[bt];
    if (hh == 0) { bS[g8] = b; tS[g8] = t; uS[g8] = u; }
    invS[g8][hh] = 1.f / den[((size_t)bt * U_ + u) * H_ + hh];
  }
  __syncthreads();
  const int sub = tid >> 7, lt = tid & 127;
  const int d = lt * 4;
  const int h = lt >> 5;
  float4 acc[4];
  acc[0] = acc[1] = acc[2] = acc[3] = make_float4(0.f, 0.f, 0.f, 0.f);
  for (int c0 = 0; c0 < C_; c0 += KC) {
#pragma unroll
    for (int p = 0; p < 8; ++p) {
      int idx = tid + p * 256;
      int cc = idx & 63;
      int rest = idx >> 6;
      int hh = rest & 3, gg = (rest >> 2) & 3, ss = rest >> 4;
      int g8 = ss * 4 + gg;
      int c = c0 + cc;
      float w = 0.f;
      if (c < C_) {
        int b = bS[g8], t = tS[g8], u = uS[g8];
        float em = EM[(((size_t)b * T_ + t) * H_ + hh) * C_ + c];
        float eh = EH[(((size_t)b * U_ + u) * H_ + hh) * C_ + c];
        w = em * eh * invS[g8][hh];
      }
      wS[ss][gg][hh][cc] = w;
    }
    __syncthreads();
#pragma unroll 4
    for (int q = 0; q < KC / 4; ++q) {
      const float4 w0 = *(const float4*)&wS[sub][0][h][q * 4];
      const float4 w1 = *(const float4*)&wS[sub][1][h][q * 4];
      const float4 w2 = *(const float4*)&wS[sub][2][h][q * 4];
      const float4 w3 = *(const float4*)&wS[sub][3][h][q * 4];
      int c = c0 + q * 4;
      float4 v;
      if (c < C_) { v = *(const float4*)&vmat[(size_t)c * D_ + d];
        fma4(acc[0], w0.x, v); fma4(acc[1], w1.x, v); fma4(acc[2], w2.x, v); fma4(acc[3], w3.x, v); }
      if (c + 1 < C_) { v = *(const float4*)&vmat[(size_t)(c + 1) * D_ + d];
        fma4(acc[0], w0.y, v); fma4(acc[1], w1.y, v); fma4(acc[2], w2.y, v); fma4(acc[3], w3.y, v); }
      if (c + 2 < C_) { v = *(const float4*)&vmat[(size_t)(c + 2) * D_ + d];
        fma4(acc[0], w0.z, v); fma4(acc[1], w1.z, v); fma4(acc[2], w2.z, v); fma4(acc[3], w3.z, v); }
      if (c + 3 < C_) { v = *(const float4*)&vmat[(size_t)(c + 3) * D_ + d];
        fma4(acc[0], w0.w, v); fma4(acc[1], w1.w, v); fma4(acc[2], w2.w, v); fma4(acc[3], w3.w, v); }
    }
    __syncthreads();
  }
#pragma unroll
  for (int g = 0; g < 4; ++g) {
    int bt = (bS[sub * 4 + g] << 7) + tS[sub * 4 + g];
    *(float4*)&aout[(size_t)bt * D_ + d] = acc[g];
  }
}

// ---------------- host launch ----------------
extern "C" void kernel_launch(void* const* d_in, const int* in_sizes, int n_in,
                              void* d_out, int out_size, void* d_ws, size_t ws_size,
                              hipStream_t stream) {
  const float* model_embed = (const float*)d_in[0];
  const float* emb_table   = (const float*)d_in[1];
  const float* Wih_f = (const float*)d_in[2];
  const float* Whh_f = (const float*)d_in[3];
  const float* b_f   = (const float*)d_in[4];
  const float* Wih_b = (const float*)d_in[5];
  const float* Whh_b = (const float*)d_in[6];
  const float* b_b   = (const float*)d_in[7];
  const float* ctx_out_W  = (const float*)d_in[8];
  const float* hist_Wih   = (const float*)d_in[9];
  const float* hist_Whh   = (const float*)d_in[10];
  const float* hist_b     = (const float*)d_in[11];
  const float* hist_out_W = (const float*)d_in[12];
  const float* Wq = (const float*)d_in[13];
  const float* Wk = (const float*)d_in[14];
  const float* Wv = (const float*)d_in[15];
  const float* Wo = (const float*)d_in[16];
  const float* acoustic_W = (const float*)d_in[17];
  const int* ctx_idxs = (const int*)d_in[18];
  const int* hidx     = (const int*)d_in[19];
  const int* ilens    = (const int*)d_in[20];

  if (ws_size < WS_NEED * sizeof(float)) return;

  float* ws = (float*)d_ws;
  float* o_out     = (float*)d_out;
  float* logit_out = o_out + (size_t)B_ * T_ * D_;
  float* prob_out  = logit_out + (size_t)B_ * T_ * U_ * C_;

  // zero: ctx h_ping + c_state (adjacent), grid-barrier state
  hipMemsetAsync(ws + HPING, 0, 4ul * C_ * E_ * sizeof(float), stream);
  hipMemsetAsync(ws + BAR_, 0, 2 * sizeof(int), stream);

  // ---- weight folding: Wqa = Wq @ acoustic_W, Wqh = Wq @ hist_out_W ----
  k_gemm_nn<<<dim3(8, 8, 2), 256, 0, stream>>>(
      Wq, acoustic_W, ws + WQA, Wq, hist_out_W, ws + WQH);

  // ---- ctx LSTM input projections for the WHOLE VOCAB (both dirs) ----
  {
    GemmB pf{};
    pf.A = emb_table; pf.lda = E_;
    pf.W = Wih_f; pf.ldw = E_;
    pf.bias = b_f;
    pf.out = ws + XZ_; pf.ldc = E4_;
    pf.M = VOC_; pf.N = E4_; pf.K = E_; pf.scale = 1.f;
    GemmB pb = pf;
    pb.W = Wih_b; pb.bias = b_b; pb.out = ws + XZ_ + (size_t)VOC_ * E4_;
    k_gemm_bigx2<<<dim3(8, (VOC_ + 127) / 128, 2), 256, 0, stream>>>(pf, pb, 1);
  }

  // ---- ctx LSTM recurrence: 8 fused steps ----
  for (int t = 0; t < L_; ++t) {
    float* hp = ws + ((t & 1) ? HPONG : HPING);
    float* hn = ws + ((t & 1) ? HPING : HPONG);
    k_ctx_step<<<dim3(4, 32, 2), 256, 0, stream>>>(
        ws + XZ_, ctx_idxs, Whh_f, Whh_b, hp, hn, ws + CST,
        ws + HFALL, ws + HBALL, t);
  }

  // ---- masked mean + ctx_out projection ----
  k_ctx_mean<<<dim3((C_ * 2 * E_ + 255) / 256), 256, 0, stream>>>(
      ws + HFALL, ws + HBALL, ilens, ws + CATM);
  {
    GemmP p{};
    p.A1 = ws + CATM; p.lda1 = 2 * E_;
    p.W1 = ctx_out_W; p.ldw1 = 2 * E_;
    p.out = ws + CTXM; p.ldc = D_; p.M = C_; p.N = D_; p.K = 2 * E_; p.scale = 1.f;
    k_gemm64<<<dim3(8, 16, 1), 256, 0, stream>>>(p);
  }

  // ---- k (scaled), v, hist input projection — one launch ----
  {
    GemmP pk{};
    pk.A1 = ws + CTXM; pk.lda1 = D_;
    pk.W1 = Wk; pk.ldw1 = D_;
    pk.out = ws + KWS; pk.ldc = D_; pk.M = C_; pk.N = D_; pk.K = D_; pk.scale = SCALE_;
    GemmP pv = pk;
    pv.W1 = Wv; pv.out = ws + VWS; pv.scale = 1.f;
    GemmP ph{};
    ph.A1 = ws + CTXM; ph.lda1 = D_;
    ph.ridx = hidx; ph.ridx_stride = 1; ph.ridx_off = 0;
    ph.W1 = hist_Wih; ph.ldw1 = D_;
    ph.bias = hist_b;
    ph.out = ws + HXP; ph.ldc = D4_; ph.M = B_ * U_; ph.N = D4_; ph.K = D_; ph.scale = 1.f;
    k_gemm64x3<<<dim3(32, 16, 3), 256, 0, stream>>>(pk, pv, ph);
  }

  // ---- persistent hist LSTM (1 launch, 16 steps, grid barrier) ----
  k_hist_fused<<<dim3(256), 256, 0, stream>>>(
      ws + HXP, hist_Whh, ws + HALL, ws + HGLOB,
      (int*)(ws + BAR_), (int*)(ws + BAR_) + 1);

  // ---- qm = model_embed @ Wqa^T ; qh = hall @ Wqh^T ----
  {
    GemmP pm{};
    pm.A1 = model_embed; pm.lda1 = D_;
    pm.W1 = ws + WQA; pm.ldw1 = D_;
    pm.out = ws + QM_; pm.ldc = D_; pm.M = B_ * T_; pm.N = D_; pm.K = D_; pm.scale = 1.f;
    GemmP ph = pm;
    ph.A1 = ws + HALL; ph.W1 = ws + WQH; ph.out = ws + QH_; ph.M = B_ * U_;
    k_gemm64x2<<<dim3(8, 16, 2), 256, 0, stream>>>(pm, ph, 1);
  }

  // ---- Sm, Sh (per-head via z) — big tiles ----
  {
    GemmB pm{};
    pm.A = ws + QM_; pm.lda = D_;
    pm.W = ws + KWS; pm.ldw = D_;
    pm.out = ws + SM_; pm.ldc = HC_; pm.M = B_ * T_; pm.N = C_; pm.K = DH_; pm.scale = 1.f;
    pm.a_zoff = DH_; pm.w_zoff = DH_; pm.c_zoff = C_;
    GemmB ph = pm;
    ph.A = ws + QH_; ph.out = ws + SH_; ph.M = B_ * U_;
    k_gemm_bigx2<<<dim3(8, 8, 8), 256, 0, stream>>>(pm, ph, 4);
  }

  // ---- exp factorization + outputs (+ decode bits fused) ----
  k_rowexp<<<dim3(B_ * T_ + B_ * U_), 256, 0, stream>>>(
      ws + SM_, ws + SH_, ws + SMSUM, ws + SHSUM);
  k_problogit<<<dim3(B_ * T_), 256, 0, stream>>>(
      ws + SM_, ws + SH_, ws + SMSUM, ws + SHSUM, hidx,
      ws + DEN_, prob_out, logit_out, (unsigned char*)(ws + BITS_));

  // ---- decode scan ----
  k_scan<<<dim3(1), 64, 0, stream>>>((const unsigned char*)(ws + BITS_), (int*)(ws + USEL_));

  // ---- PV on the 1024 selected rows only ----
  k_pvg<<<dim3(128), 256, 0, stream>>>(
      ws + SM_, ws + SH_, ws + DEN_, (const int*)(ws + USEL_), ws + VWS, ws + AOUT_);

  // ---- Wo projection on selected rows -> o ----
  {
    GemmP p{};
    p.A1 = ws + AOUT_; p.lda1 = D_;
    p.W1 = Wo; p.ldw1 = D_;
    p.out = o_out; p.ldc = D_; p.M = B_ * T_; p.N = D_; p.K = D_; p.scale = 1.f;
    k_gemm64<<<dim3(8, 16, 1), 256, 0, stream>>>(p);
  }
}